// Round 1
// baseline (444.850 us; speedup 1.0000x reference)
//
#include <hip/hip_runtime.h>
#include <math.h>

static constexpr int N_NODES = 20000;
static constexpr int N_EDGES = 320000;
static constexpr int ETOT    = N_EDGES + N_NODES;   // edges + self loops
static constexpr float LN_EPS = 1e-5f;

__device__ __forceinline__ float lrelu02(float x){ return x > 0.f ? x : 0.2f*x; }
__device__ __forceinline__ float gelu_ex(float x){ return 0.5f*x*(1.f+erff(x*0.70710678118654752f)); }

// ---------------- LN over input rows (128) ----------------
__global__ void k_ln_in(const float* __restrict__ x, const float* __restrict__ g,
                        const float* __restrict__ b, float* __restrict__ out) {
  __shared__ float scr[2];
  int n = blockIdx.x, t = threadIdx.x;          // block = 128
  size_t base = (size_t)n*128;
  float v = x[base+t];
  float s = v;
  #pragma unroll
  for (int o=32;o>0;o>>=1) s += __shfl_down(s,o);
  if ((t&63)==0) scr[t>>6]=s;
  __syncthreads();
  float mu = (scr[0]+scr[1]) * (1.f/128.f);
  __syncthreads();
  float dd = v-mu, q = dd*dd;
  #pragma unroll
  for (int o=32;o>0;o>>=1) q += __shfl_down(q,o);
  if ((t&63)==0) scr[t>>6]=q;
  __syncthreads();
  float var = (scr[0]+scr[1]) * (1.f/128.f);
  out[base+t] = dd*rsqrtf(var+LN_EPS)*g[t]+b[t];
}

// ---------------- fp32 tiled GEMM: C[M,N] = A[M,K] @ B[K,N] ----------------
// BM=128 BN=64 BK=32 TM=8 TN=4, 256 threads
__global__ __launch_bounds__(256) void k_gemm(const float* __restrict__ A,
    const float* __restrict__ B, float* __restrict__ C, int M, int N, int K) {
  constexpr int BM=128, BN=64, BK=32;
  __shared__ __align__(16) float As[BK][BM+4];
  __shared__ __align__(16) float Bs[BK][BN];
  int tid = threadIdx.x;
  int bm = blockIdx.y*BM, bn = blockIdx.x*BN;
  int tr = tid >> 4, tc = tid & 15;
  float acc[8][4] = {};
  for (int k0 = 0; k0 < K; k0 += BK) {
    #pragma unroll
    for (int sweep = 0; sweep < 4; ++sweep) {      // A tile 128x32
      int i0 = sweep*1024 + tid*4;
      int r = i0 >> 5, c = i0 & 31;
      int gr = bm + r;
      float4 val = make_float4(0.f,0.f,0.f,0.f);
      if (gr < M) val = *(const float4*)&A[(size_t)gr*K + k0 + c];
      As[c][r] = val.x; As[c+1][r]=val.y; As[c+2][r]=val.z; As[c+3][r]=val.w;
    }
    #pragma unroll
    for (int sweep = 0; sweep < 2; ++sweep) {      // B tile 32x64
      int i0 = sweep*1024 + tid*4;
      int r = i0 >> 6, c = i0 & 63;
      *(float4*)&Bs[r][c] = *(const float4*)&B[(size_t)(k0+r)*N + bn + c];
    }
    __syncthreads();
    #pragma unroll
    for (int kk=0; kk<BK; ++kk) {
      float4 a0 = *(const float4*)&As[kk][tr*8];
      float4 a1 = *(const float4*)&As[kk][tr*8+4];
      float4 bv = *(const float4*)&Bs[kk][tc*4];
      float av[8] = {a0.x,a0.y,a0.z,a0.w,a1.x,a1.y,a1.z,a1.w};
      float bw[4] = {bv.x,bv.y,bv.z,bv.w};
      #pragma unroll
      for (int i=0;i<8;i++)
        #pragma unroll
        for (int j=0;j<4;j++)
          acc[i][j] += av[i]*bw[j];
    }
    __syncthreads();
  }
  #pragma unroll
  for (int i=0;i<8;i++){
    int gr = bm + tr*8 + i;
    if (gr >= M) continue;
    float4 o = make_float4(acc[i][0],acc[i][1],acc[i][2],acc[i][3]);
    *(float4*)&C[(size_t)gr*N + bn + tc*4] = o;
  }
}

// ---------------- attention logits, layer1: 4 heads x 128 ----------------
__global__ void k_att1(const float* __restrict__ xh, const float* __restrict__ as_,
                       const float* __restrict__ ad_, float* __restrict__ als,
                       float* __restrict__ ald) {
  int n = blockIdx.x, t = threadIdx.x;            // block = 64
  size_t base = (size_t)n*512;
  float ps[4], pd[4];
  #pragma unroll
  for (int h=0;h<4;h++){
    float v0 = xh[base + h*128 + t];
    float v1 = xh[base + h*128 + 64 + t];
    ps[h] = v0*as_[h*128+t] + v1*as_[h*128+64+t];
    pd[h] = v0*ad_[h*128+t] + v1*ad_[h*128+64+t];
  }
  #pragma unroll
  for (int o=32;o>0;o>>=1){
    #pragma unroll
    for (int h=0;h<4;h++){ ps[h]+=__shfl_down(ps[h],o); pd[h]+=__shfl_down(pd[h],o); }
  }
  if (t==0){
    *(float4*)&als[(size_t)n*4] = make_float4(ps[0],ps[1],ps[2],ps[3]);
    *(float4*)&ald[(size_t)n*4] = make_float4(pd[0],pd[1],pd[2],pd[3]);
  }
}

// ---------------- attention logits, layer2: 1 head x 128 ----------------
__global__ void k_att2(const float* __restrict__ xh, const float* __restrict__ as_,
                       const float* __restrict__ ad_, float* __restrict__ als,
                       float* __restrict__ ald) {
  int n = blockIdx.x, t = threadIdx.x;            // block = 64
  size_t base = (size_t)n*128;
  float v0 = xh[base+t], v1 = xh[base+64+t];
  float ps = v0*as_[t] + v1*as_[64+t];
  float pd = v0*ad_[t] + v1*ad_[64+t];
  #pragma unroll
  for (int o=32;o>0;o>>=1){ ps+=__shfl_down(ps,o); pd+=__shfl_down(pd,o); }
  if (t==0){ als[n]=ps; ald[n]=pd; }
}

// ---------------- CSR build ----------------
__global__ void k_count(const int* __restrict__ ei, int* __restrict__ cnt) {
  int e = blockIdx.x*256 + threadIdx.x;
  if (e < N_EDGES) atomicAdd(&cnt[ei[N_EDGES + e]], 1);
  else if (e < ETOT) atomicAdd(&cnt[e - N_EDGES], 1);
}

__global__ void k_scan1(const int* __restrict__ cnt, int* __restrict__ offs,
                        int* __restrict__ blksum) {
  __shared__ int s[256];
  int i = blockIdx.x*256 + threadIdx.x;
  int v = (i < N_NODES) ? cnt[i] : 0;
  s[threadIdx.x] = v;
  __syncthreads();
  for (int d1=1; d1<256; d1<<=1){
    int t = (threadIdx.x >= d1) ? s[threadIdx.x - d1] : 0;
    __syncthreads();
    s[threadIdx.x] += t;
    __syncthreads();
  }
  if (i < N_NODES) offs[i] = s[threadIdx.x] - v;   // exclusive
  if (threadIdx.x == 255) blksum[blockIdx.x] = s[255];
}

__global__ void k_scan2(int* __restrict__ blksum, int nb) {
  if (threadIdx.x==0 && blockIdx.x==0){
    int run=0;
    for (int i=0;i<nb;i++){ int v=blksum[i]; blksum[i]=run; run+=v; }
  }
}

__global__ void k_scan3(int* __restrict__ offs, const int* __restrict__ blksum) {
  int i = blockIdx.x*256 + threadIdx.x;
  if (i < N_NODES) offs[i] += blksum[blockIdx.x];
}

__global__ void k_scatter(const int* __restrict__ ei, const int* __restrict__ offs,
                          int* __restrict__ cur, int* __restrict__ csr) {
  int e = blockIdx.x*256 + threadIdx.x;
  int s, d;
  if (e < N_EDGES){ s = ei[e]; d = ei[N_EDGES+e]; }
  else if (e < ETOT){ s = e - N_EDGES; d = s; }
  else return;
  int pos = offs[d] + atomicAdd(&cur[d], 1);
  csr[pos] = s;
}

// ---------------- GAT layer 1 aggregate + bias + LN + GELU ----------------
// one block (256 thr) per dst node; 4 heads x 128 ch = 512 ch
__global__ __launch_bounds__(256) void k_gat1(
    const float* __restrict__ xh,                  // [N,512]
    const float* __restrict__ als, const float* __restrict__ ald, // [N,4]
    const int* __restrict__ offs, const int* __restrict__ cnt, const int* __restrict__ csr,
    const float* __restrict__ bias1, const float* __restrict__ g1, const float* __restrict__ b1,
    float* __restrict__ out)                       // [N,512]
{
  int d = blockIdx.x, tid = threadIdx.x;
  int start = offs[d], deg = cnt[d];
  __shared__ float wred[4][4];
  __shared__ float mS[4], iS[4];
  __shared__ float alphaS[4][64];
  __shared__ int   srcS[64];
  __shared__ float scr[4];
  int wid = tid>>6;
  float4 ad4 = *(const float4*)&ald[(size_t)d*4];
  float aldd[4] = {ad4.x, ad4.y, ad4.z, ad4.w};

  // pass A: per-head max of leaky_relu(al_s[src]+al_d[d])
  float ml[4] = {-1e30f,-1e30f,-1e30f,-1e30f};
  for (int i=tid;i<deg;i+=256){
    int s = csr[start+i];
    float4 a4 = *(const float4*)&als[(size_t)s*4];
    ml[0]=fmaxf(ml[0],lrelu02(a4.x+aldd[0]));
    ml[1]=fmaxf(ml[1],lrelu02(a4.y+aldd[1]));
    ml[2]=fmaxf(ml[2],lrelu02(a4.z+aldd[2]));
    ml[3]=fmaxf(ml[3],lrelu02(a4.w+aldd[3]));
  }
  #pragma unroll
  for (int h=0;h<4;h++)
    for (int o=32;o>0;o>>=1) ml[h]=fmaxf(ml[h],__shfl_down(ml[h],o));
  if ((tid&63)==0){
    #pragma unroll
    for (int h=0;h<4;h++) wred[wid][h]=ml[h];
  }
  __syncthreads();
  if (tid<4)
    mS[tid] = fmaxf(fmaxf(wred[0][tid],wred[1][tid]),fmaxf(wred[2][tid],wred[3][tid]));
  __syncthreads();
  float mh[4] = {mS[0],mS[1],mS[2],mS[3]};

  // pass B: per-head sum of exp
  float sl[4]={0.f,0.f,0.f,0.f};
  for (int i=tid;i<deg;i+=256){
    int s = csr[start+i];
    float4 a4 = *(const float4*)&als[(size_t)s*4];
    sl[0]+=expf(lrelu02(a4.x+aldd[0])-mh[0]);
    sl[1]+=expf(lrelu02(a4.y+aldd[1])-mh[1]);
    sl[2]+=expf(lrelu02(a4.z+aldd[2])-mh[2]);
    sl[3]+=expf(lrelu02(a4.w+aldd[3])-mh[3]);
  }
  #pragma unroll
  for (int h=0;h<4;h++)
    for (int o=32;o>0;o>>=1) sl[h]+=__shfl_down(sl[h],o);
  if ((tid&63)==0){
    #pragma unroll
    for (int h=0;h<4;h++) wred[wid][h]=sl[h];
  }
  __syncthreads();
  if (tid<4)
    iS[tid] = 1.f/(wred[0][tid]+wred[1][tid]+wred[2][tid]+wred[3][tid]);
  __syncthreads();
  float inv[4] = {iS[0],iS[1],iS[2],iS[3]};

  // pass C: chunked weighted gather-accumulate; thread owns channels tid, tid+256
  float acc0=0.f, acc1=0.f;
  int c0 = tid, c1 = tid+256;
  int h0 = tid>>7, h1 = h0+2;
  for (int cb=0; cb<deg; cb+=64){
    int mm = min(64, deg-cb);
    __syncthreads();
    {
      int i = tid & 63, h = tid >> 6;
      if (i < mm){
        int s = csr[start+cb+i];
        if (h==0) srcS[i]=s;
        float e = lrelu02(als[(size_t)s*4+h]+aldd[h]);
        alphaS[h][i] = expf(e-mh[h])*inv[h];
      }
    }
    __syncthreads();
    for (int j=0;j<mm;j++){
      const float* row = xh + (size_t)srcS[j]*512;
      acc0 += alphaS[h0][j]*row[c0];
      acc1 += alphaS[h1][j]*row[c1];
    }
  }
  float v0 = acc0 + bias1[c0];
  float v1 = acc1 + bias1[c1];

  // fused LN(512) + GELU
  float s1 = v0+v1;
  for (int o=32;o>0;o>>=1) s1 += __shfl_down(s1,o);
  if ((tid&63)==0) scr[wid]=s1;
  __syncthreads();
  float mu = (scr[0]+scr[1]+scr[2]+scr[3])*(1.f/512.f);
  __syncthreads();
  float d0=v0-mu, d1=v1-mu;
  float q = d0*d0+d1*d1;
  for (int o=32;o>0;o>>=1) q += __shfl_down(q,o);
  if ((tid&63)==0) scr[wid]=q;
  __syncthreads();
  float var = (scr[0]+scr[1]+scr[2]+scr[3])*(1.f/512.f);
  float rs = rsqrtf(var+LN_EPS);
  size_t ob = (size_t)d*512;
  out[ob+c0] = gelu_ex(d0*rs*g1[c0]+b1[c0]);
  out[ob+c1] = gelu_ex(d1*rs*g1[c1]+b1[c1]);
}

// ------- GAT layer 2 aggregate + bias + LN + GELU + Wo proj + log_softmax -------
// one block (128 thr) per dst node
__global__ __launch_bounds__(128) void k_gat2_final(
    const float* __restrict__ xh,                  // [N,128]
    const float* __restrict__ als, const float* __restrict__ ald, // [N]
    const int* __restrict__ offs, const int* __restrict__ cnt, const int* __restrict__ csr,
    const float* __restrict__ bias2, const float* __restrict__ g2, const float* __restrict__ b2,
    const float* __restrict__ Wo, const float* __restrict__ bo,
    float* __restrict__ out)                       // [N,32]
{
  int d = blockIdx.x, tid = threadIdx.x;
  int start = offs[d], deg = cnt[d];
  __shared__ float scr[2];
  __shared__ float lseS;
  __shared__ float alphaS[64];
  __shared__ int   srcS[64];
  __shared__ float hS[128];
  __shared__ float lS[32];
  float add = ald[d];

  float ml = -1e30f;
  for (int i=tid;i<deg;i+=128){
    int s = csr[start+i];
    ml = fmaxf(ml, lrelu02(als[s]+add));
  }
  for (int o=32;o>0;o>>=1) ml = fmaxf(ml,__shfl_down(ml,o));
  if ((tid&63)==0) scr[tid>>6]=ml;
  __syncthreads();
  float m = fmaxf(scr[0],scr[1]);
  __syncthreads();
  float sl = 0.f;
  for (int i=tid;i<deg;i+=128){
    int s = csr[start+i];
    sl += expf(lrelu02(als[s]+add)-m);
  }
  for (int o=32;o>0;o>>=1) sl += __shfl_down(sl,o);
  if ((tid&63)==0) scr[tid>>6]=sl;
  __syncthreads();
  float inv = 1.f/(scr[0]+scr[1]);
  __syncthreads();

  float acc = 0.f;
  for (int cb=0; cb<deg; cb+=64){
    int mm = min(64, deg-cb);
    __syncthreads();
    if (tid < mm){
      int s = csr[start+cb+tid];
      srcS[tid] = s;
      alphaS[tid] = expf(lrelu02(als[s]+add)-m)*inv;
    }
    __syncthreads();
    for (int j=0;j<mm;j++)
      acc += alphaS[j]*xh[(size_t)srcS[j]*128 + tid];
  }
  float v = acc + bias2[tid];

  // LN(128)
  float s1 = v;
  for (int o=32;o>0;o>>=1) s1 += __shfl_down(s1,o);
  if ((tid&63)==0) scr[tid>>6]=s1;
  __syncthreads();
  float mu = (scr[0]+scr[1])*(1.f/128.f);
  __syncthreads();
  float dd = v-mu, q = dd*dd;
  for (int o=32;o>0;o>>=1) q += __shfl_down(q,o);
  if ((tid&63)==0) scr[tid>>6]=q;
  __syncthreads();
  float var = (scr[0]+scr[1])*(1.f/128.f);
  float y = gelu_ex(dd*rsqrtf(var+LN_EPS)*g2[tid]+b2[tid]);
  hS[tid] = y;
  __syncthreads();

  // final projection (128 -> 32) + log_softmax
  if (tid < 32){
    float a = bo[tid];
    #pragma unroll 8
    for (int k=0;k<128;k++) a += hS[k]*Wo[k*32+tid];
    lS[tid] = a;
  }
  __syncthreads();
  if (tid == 0){
    float mx = -1e30f;
    for (int j=0;j<32;j++) mx = fmaxf(mx, lS[j]);
    float se = 0.f;
    for (int j=0;j<32;j++) se += expf(lS[j]-mx);
    lseS = mx + logf(se);
  }
  __syncthreads();
  if (tid < 32) out[(size_t)d*32+tid] = lS[tid]-lseS;
}

extern "C" void kernel_launch(void* const* d_in, const int* in_sizes, int n_in,
                              void* d_out, int out_size, void* d_ws, size_t ws_size,
                              hipStream_t stream) {
  const float* x      = (const float*)d_in[0];
  const int*   ei     = (const int*)d_in[1];
  const float* g_in   = (const float*)d_in[2];
  const float* b_in   = (const float*)d_in[3];
  const float* W1     = (const float*)d_in[4];
  const float* att1_s = (const float*)d_in[5];
  const float* att1_d = (const float*)d_in[6];
  const float* bias1  = (const float*)d_in[7];
  const float* g1     = (const float*)d_in[8];
  const float* b1     = (const float*)d_in[9];
  const float* W2     = (const float*)d_in[10];
  const float* att2_s = (const float*)d_in[11];
  const float* att2_d = (const float*)d_in[12];
  const float* bias2  = (const float*)d_in[13];
  const float* g2     = (const float*)d_in[14];
  const float* b2     = (const float*)d_in[15];
  const float* Wo     = (const float*)d_in[16];
  const float* bo     = (const float*)d_in[17];
  float* out = (float*)d_out;

  char* ws = (char*)d_ws;
  size_t off = 0;
  auto alloc = [&](size_t bytes)->char*{
    char* p = ws + off; off += (bytes + 255) & ~(size_t)255; return p;
  };
  float* h0     = (float*)alloc((size_t)N_NODES*128*4);   // LN(x); later reused as xh2
  float* xh1    = (float*)alloc((size_t)N_NODES*512*4);
  float* h1post = (float*)alloc((size_t)N_NODES*512*4);
  float* als1   = (float*)alloc((size_t)N_NODES*4*4);
  float* ald1   = (float*)alloc((size_t)N_NODES*4*4);
  float* als2   = (float*)alloc((size_t)N_NODES*4);
  float* ald2   = (float*)alloc((size_t)N_NODES*4);
  int*   cnt    = (int*)alloc((size_t)N_NODES*4);
  int*   cur    = (int*)alloc((size_t)N_NODES*4);
  int*   offs   = (int*)alloc((size_t)N_NODES*4);
  int*   blksum = (int*)alloc(4096);
  int*   csr    = (int*)alloc((size_t)ETOT*4);
  float* xh2    = h0;   // reuse: h0 dead after GEMM1

  hipMemsetAsync(cnt, 0, (size_t)N_NODES*4, stream);
  hipMemsetAsync(cur, 0, (size_t)N_NODES*4, stream);

  int ebl = (ETOT + 255)/256;
  int nbl = (N_NODES + 255)/256;

  // CSR build (depends only on edge_index)
  k_count  <<<ebl,256,0,stream>>>(ei, cnt);
  k_scan1  <<<nbl,256,0,stream>>>(cnt, offs, blksum);
  k_scan2  <<<1,64,0,stream>>>(blksum, nbl);
  k_scan3  <<<nbl,256,0,stream>>>(offs, blksum);
  k_scatter<<<ebl,256,0,stream>>>(ei, offs, cur, csr);

  // layer pipeline
  k_ln_in<<<N_NODES,128,0,stream>>>(x, g_in, b_in, h0);
  k_gemm<<<dim3(512/64,(N_NODES+127)/128),256,0,stream>>>(h0, W1, xh1, N_NODES, 512, 128);
  k_att1<<<N_NODES,64,0,stream>>>(xh1, att1_s, att1_d, als1, ald1);
  k_gat1<<<N_NODES,256,0,stream>>>(xh1, als1, ald1, offs, cnt, csr, bias1, g1, b1, h1post);
  k_gemm<<<dim3(128/64,(N_NODES+127)/128),256,0,stream>>>(h1post, W2, xh2, N_NODES, 128, 512);
  k_att2<<<N_NODES,64,0,stream>>>(xh2, att2_s, att2_d, als2, ald2);
  k_gat2_final<<<N_NODES,128,0,stream>>>(xh2, als2, ald2, offs, cnt, csr,
                                         bias2, g2, b2, Wo, bo, out);
}

// Round 3
// 367.493 us; speedup vs baseline: 1.2105x; 1.2105x over previous
//
#include <hip/hip_runtime.h>
#include <hip/hip_bf16.h>
#include <math.h>

static constexpr int N_NODES = 20000;
static constexpr int N_EDGES = 320000;
static constexpr int ETOT    = N_EDGES + N_NODES;   // edges + self loops
static constexpr float LN_EPS = 1e-5f;

__device__ __forceinline__ float lrelu02(float x){ return x > 0.f ? x : 0.2f*x; }
__device__ __forceinline__ float gelu_ex(float x){ return 0.5f*x*(1.f+erff(x*0.70710678118654752f)); }
__device__ __forceinline__ float bflo(unsigned u){ return __uint_as_float(u<<16); }
__device__ __forceinline__ float bfhi(unsigned u){ return __uint_as_float(u & 0xffff0000u); }
__device__ __forceinline__ unsigned f2bf(float f){           // RNE fp32->bf16 (no NaN inputs here)
  unsigned u = __float_as_uint(f);
  return (u + 0x7fffu + ((u>>16)&1u)) >> 16;
}
__device__ __forceinline__ unsigned packbf2(float a, float b){ return f2bf(a) | (f2bf(b)<<16); }

// ---------------- LN over input rows (128) -> bf16 ----------------
__global__ __launch_bounds__(64) void k_ln_in(const float* __restrict__ x,
    const float* __restrict__ g, const float* __restrict__ b, unsigned* __restrict__ out) {
  int n = blockIdx.x, t = threadIdx.x;               // block = 64, 2 ch/thread
  float2 v = ((const float2*)(x + (size_t)n*128))[t];
  float s = v.x + v.y;
  #pragma unroll
  for (int o=32;o>0;o>>=1) s += __shfl_down(s,o);
  s = __shfl(s,0);
  float mu = s*(1.f/128.f);
  float d0 = v.x-mu, d1 = v.y-mu;
  float q = d0*d0+d1*d1;
  #pragma unroll
  for (int o=32;o>0;o>>=1) q += __shfl_down(q,o);
  q = __shfl(q,0);
  float rs = rsqrtf(q*(1.f/128.f)+LN_EPS);
  float2 gg = ((const float2*)g)[t];
  float2 bb = ((const float2*)b)[t];
  out[(size_t)n*64 + t] = packbf2(d0*rs*gg.x+bb.x, d1*rs*gg.y+bb.y);
}

// -------- fp32-accum GEMM, bf16 A, fp32 B; writes C fp32 + Cb bf16 --------
// BM=128 BN=64 BK=32 TM=8 TN=4, 256 threads
__global__ __launch_bounds__(256) void k_gemm(const __hip_bfloat16* __restrict__ A,
    const float* __restrict__ B, float* __restrict__ C, unsigned* __restrict__ Cb,
    int M, int N, int K) {
  constexpr int BM=128, BN=64, BK=32;
  __shared__ __align__(16) float As[BK][BM+4];
  __shared__ __align__(16) float Bs[BK][BN];
  int tid = threadIdx.x;
  int bm = blockIdx.y*BM, bn = blockIdx.x*BN;
  int tr = tid >> 4, tc = tid & 15;
  float acc[8][4] = {};
  for (int k0 = 0; k0 < K; k0 += BK) {
    #pragma unroll
    for (int sweep = 0; sweep < 2; ++sweep) {        // A tile 128x32 bf16, 8 elems/thread
      int i0 = sweep*2048 + tid*8;
      int r = i0 >> 5, c = i0 & 31;
      int gr = bm + r;
      uint4 u = make_uint4(0u,0u,0u,0u);
      if (gr < M) u = *(const uint4*)&A[(size_t)gr*K + k0 + c];
      As[c+0][r]=bflo(u.x); As[c+1][r]=bfhi(u.x);
      As[c+2][r]=bflo(u.y); As[c+3][r]=bfhi(u.y);
      As[c+4][r]=bflo(u.z); As[c+5][r]=bfhi(u.z);
      As[c+6][r]=bflo(u.w); As[c+7][r]=bfhi(u.w);
    }
    #pragma unroll
    for (int sweep = 0; sweep < 2; ++sweep) {        // B tile 32x64 fp32
      int i0 = sweep*1024 + tid*4;
      int r = i0 >> 6, c = i0 & 63;
      *(float4*)&Bs[r][c] = *(const float4*)&B[(size_t)(k0+r)*N + bn + c];
    }
    __syncthreads();
    #pragma unroll
    for (int kk=0; kk<BK; ++kk) {
      float4 a0 = *(const float4*)&As[kk][tr*8];
      float4 a1 = *(const float4*)&As[kk][tr*8+4];
      float4 bv = *(const float4*)&Bs[kk][tc*4];
      float av[8] = {a0.x,a0.y,a0.z,a0.w,a1.x,a1.y,a1.z,a1.w};
      float bw[4] = {bv.x,bv.y,bv.z,bv.w};
      #pragma unroll
      for (int i=0;i<8;i++)
        #pragma unroll
        for (int j=0;j<4;j++)
          acc[i][j] += av[i]*bw[j];
    }
    __syncthreads();
  }
  #pragma unroll
  for (int i=0;i<8;i++){
    int gr = bm + tr*8 + i;
    if (gr >= M) continue;
    size_t o = (size_t)gr*N + bn + tc*4;
    float4 v = make_float4(acc[i][0],acc[i][1],acc[i][2],acc[i][3]);
    *(float4*)&C[o] = v;
    uint2 p; p.x = packbf2(v.x,v.y); p.y = packbf2(v.z,v.w);
    *(uint2*)&Cb[o>>1] = p;
  }
}

// ---------------- attention logits, layer1 (reads fp32 xh) ----------------
__global__ __launch_bounds__(64) void k_att1(const float* __restrict__ xh,
    const float* __restrict__ as_, const float* __restrict__ ad_,
    float* __restrict__ als, float* __restrict__ ald) {
  int n = blockIdx.x, t = threadIdx.x;               // 8 ch/thread; head = t>>4
  const float* row = xh + (size_t)n*512;
  float4 v0 = ((const float4*)row)[2*t];
  float4 v1 = ((const float4*)row)[2*t+1];
  float4 w0 = ((const float4*)as_)[2*t], w1 = ((const float4*)as_)[2*t+1];
  float4 u0 = ((const float4*)ad_)[2*t], u1 = ((const float4*)ad_)[2*t+1];
  float ps = v0.x*w0.x+v0.y*w0.y+v0.z*w0.z+v0.w*w0.w
           + v1.x*w1.x+v1.y*w1.y+v1.z*w1.z+v1.w*w1.w;
  float pd = v0.x*u0.x+v0.y*u0.y+v0.z*u0.z+v0.w*u0.w
           + v1.x*u1.x+v1.y*u1.y+v1.z*u1.z+v1.w*u1.w;
  #pragma unroll
  for (int o=8;o>0;o>>=1){ ps+=__shfl_xor(ps,o); pd+=__shfl_xor(pd,o); }
  if ((t&15)==0){ int h=t>>4; als[(size_t)n*4+h]=ps; ald[(size_t)n*4+h]=pd; }
}

// ---------------- attention logits, layer2 (reads fp32 xh) ----------------
__global__ __launch_bounds__(64) void k_att2(const float* __restrict__ xh,
    const float* __restrict__ as_, const float* __restrict__ ad_,
    float* __restrict__ als, float* __restrict__ ald) {
  int n = blockIdx.x, t = threadIdx.x;               // 2 ch/thread
  float2 v = ((const float2*)(xh + (size_t)n*128))[t];
  float2 ws = ((const float2*)as_)[t], wd = ((const float2*)ad_)[t];
  float ps = v.x*ws.x+v.y*ws.y;
  float pd = v.x*wd.x+v.y*wd.y;
  #pragma unroll
  for (int o=32;o>0;o>>=1){ ps+=__shfl_down(ps,o); pd+=__shfl_down(pd,o); }
  if (t==0){ als[n]=ps; ald[n]=pd; }
}

// ---------------- CSR build ----------------
__global__ void k_count(const int* __restrict__ ei, int* __restrict__ cnt) {
  int e = blockIdx.x*256 + threadIdx.x;
  if (e < N_EDGES) atomicAdd(&cnt[ei[N_EDGES + e]], 1);
  else if (e < ETOT) atomicAdd(&cnt[e - N_EDGES], 1);
}

__global__ void k_scan1(const int* __restrict__ cnt, int* __restrict__ offs,
                        int* __restrict__ blksum) {
  __shared__ int s[256];
  int i = blockIdx.x*256 + threadIdx.x;
  int v = (i < N_NODES) ? cnt[i] : 0;
  s[threadIdx.x] = v;
  __syncthreads();
  for (int d1=1; d1<256; d1<<=1){
    int t = (threadIdx.x >= d1) ? s[threadIdx.x - d1] : 0;
    __syncthreads();
    s[threadIdx.x] += t;
    __syncthreads();
  }
  if (i < N_NODES) offs[i] = s[threadIdx.x] - v;     // exclusive
  if (threadIdx.x == 255) blksum[blockIdx.x] = s[255];
}

__global__ void k_scan2(int* __restrict__ blksum, int nb) {
  if (threadIdx.x==0 && blockIdx.x==0){
    int run=0;
    for (int i=0;i<nb;i++){ int v=blksum[i]; blksum[i]=run; run+=v; }
  }
}

__global__ void k_scan3(int* __restrict__ offs, const int* __restrict__ blksum) {
  int i = blockIdx.x*256 + threadIdx.x;
  if (i < N_NODES) offs[i] += blksum[blockIdx.x];
}

__global__ void k_scatter(const int* __restrict__ ei, const int* __restrict__ offs,
                          int* __restrict__ cur, int* __restrict__ csr) {
  int e = blockIdx.x*256 + threadIdx.x;
  int s, d;
  if (e < N_EDGES){ s = ei[e]; d = ei[N_EDGES+e]; }
  else if (e < ETOT){ s = e - N_EDGES; d = s; }
  else return;
  int pos = offs[d] + atomicAdd(&cur[d], 1);
  csr[pos] = s;
}

// ---- GAT layer 1: single-sweep softmax-aggregate + bias + LN + GELU -> bf16 ----
// one block (256 thr = 4 waves, wave w == head w) per dst node
__global__ __launch_bounds__(256) void k_gat1(
    const __hip_bfloat16* __restrict__ xh,           // [N,512] bf16
    const float* __restrict__ als, const float* __restrict__ ald, // [N,4]
    const int* __restrict__ offs, const int* __restrict__ cnt, const int* __restrict__ csr,
    const float* __restrict__ bias1, const float* __restrict__ g1, const float* __restrict__ b1,
    unsigned* __restrict__ out)                      // [N,512] bf16 (as uint pairs)
{
  int d = blockIdx.x, tid = threadIdx.x;
  int start = offs[d], deg = cnt[d];
  __shared__ float alphaS[4][64];
  __shared__ int   srcS[64];
  __shared__ float invS[4];
  __shared__ float scr[4];
  int wid = tid>>6, lane = tid&63;
  int c0 = 2*tid, c1 = 2*tid+1;                      // both channels in head `wid`
  float add = ald[(size_t)d*4 + wid];
  float den = 0.f;
  float acc0 = 0.f, acc1 = 0.f;

  for (int cb=0; cb<deg; cb+=64){
    int mm = min(64, deg-cb);
    __syncthreads();
    if (lane < mm){
      int s = csr[start+cb+lane];
      if (wid==0) srcS[lane] = s;
      float ex = expf(lrelu02(als[(size_t)s*4+wid]+add));  // logits bounded: no max pass
      alphaS[wid][lane] = ex;
      den += ex;
    }
    __syncthreads();
    int j = 0;
    for (; j+2 <= mm; j += 2){
      const unsigned* r0 = (const unsigned*)(xh + (size_t)srcS[j]*512);
      const unsigned* r1 = (const unsigned*)(xh + (size_t)srcS[j+1]*512);
      unsigned u0 = r0[tid], u1 = r1[tid];
      float a0 = alphaS[wid][j], a1 = alphaS[wid][j+1];
      acc0 += a0*bflo(u0); acc1 += a0*bfhi(u0);
      acc0 += a1*bflo(u1); acc1 += a1*bfhi(u1);
    }
    if (j < mm){
      const unsigned* r0 = (const unsigned*)(xh + (size_t)srcS[j]*512);
      unsigned u0 = r0[tid];
      float a0 = alphaS[wid][j];
      acc0 += a0*bflo(u0); acc1 += a0*bfhi(u0);
    }
  }
  #pragma unroll
  for (int o=32;o>0;o>>=1) den += __shfl_down(den,o);
  if (lane==0) invS[wid] = 1.f/den;
  __syncthreads();
  float inv = invS[wid];
  float v0 = acc0*inv + bias1[c0];
  float v1 = acc1*inv + bias1[c1];

  // fused LN(512) + GELU, then pack bf16
  float s1 = v0+v1;
  #pragma unroll
  for (int o=32;o>0;o>>=1) s1 += __shfl_down(s1,o);
  if (lane==0) scr[wid]=s1;
  __syncthreads();
  float mu = (scr[0]+scr[1]+scr[2]+scr[3])*(1.f/512.f);
  __syncthreads();
  float d0=v0-mu, d1=v1-mu;
  float q = d0*d0+d1*d1;
  #pragma unroll
  for (int o=32;o>0;o>>=1) q += __shfl_down(q,o);
  if (lane==0) scr[wid]=q;
  __syncthreads();
  float var = (scr[0]+scr[1]+scr[2]+scr[3])*(1.f/512.f);
  float rs = rsqrtf(var+LN_EPS);
  float y0 = gelu_ex(d0*rs*g1[c0]+b1[c0]);
  float y1 = gelu_ex(d1*rs*g1[c1]+b1[c1]);
  out[(size_t)d*256 + tid] = packbf2(y0,y1);
}

// -- GAT layer 2: single-sweep aggregate + bias + LN + GELU + Wo + log_softmax --
// one block = one wave (64 thr) per dst node, 2 ch/thread
__global__ __launch_bounds__(64) void k_gat2_final(
    const __hip_bfloat16* __restrict__ xh,           // [N,128] bf16
    const float* __restrict__ als, const float* __restrict__ ald, // [N]
    const int* __restrict__ offs, const int* __restrict__ cnt, const int* __restrict__ csr,
    const float* __restrict__ bias2, const float* __restrict__ g2, const float* __restrict__ b2,
    const float* __restrict__ Wo, const float* __restrict__ bo,
    float* __restrict__ out)                         // [N,32]
{
  int d = blockIdx.x, t = threadIdx.x;
  int start = offs[d], deg = cnt[d];
  __shared__ float alphaS[64];
  __shared__ int   srcS[64];
  __shared__ float hS[128];
  float add = ald[d];
  float den = 0.f, acc0 = 0.f, acc1 = 0.f;

  for (int cb=0; cb<deg; cb+=64){
    int mm = min(64, deg-cb);
    __syncthreads();
    if (t < mm){
      int s = csr[start+cb+t];
      srcS[t] = s;
      float ex = expf(lrelu02(als[s]+add));
      alphaS[t] = ex;
      den += ex;
    }
    __syncthreads();
    int j = 0;
    for (; j+2 <= mm; j += 2){
      const unsigned* r0 = (const unsigned*)(xh + (size_t)srcS[j]*128);
      const unsigned* r1 = (const unsigned*)(xh + (size_t)srcS[j+1]*128);
      unsigned u0 = r0[t], u1 = r1[t];
      float a0 = alphaS[j], a1 = alphaS[j+1];
      acc0 += a0*bflo(u0); acc1 += a0*bfhi(u0);
      acc0 += a1*bflo(u1); acc1 += a1*bfhi(u1);
    }
    if (j < mm){
      const unsigned* r0 = (const unsigned*)(xh + (size_t)srcS[j]*128);
      unsigned u0 = r0[t];
      float a0 = alphaS[j];
      acc0 += a0*bflo(u0); acc1 += a0*bfhi(u0);
    }
  }
  #pragma unroll
  for (int o=32;o>0;o>>=1) den += __shfl_down(den,o);
  den = __shfl(den,0);
  float inv = 1.f/den;
  float v0 = acc0*inv + bias2[2*t];
  float v1 = acc1*inv + bias2[2*t+1];

  // LN(128) — wave-only reductions
  float s1 = v0+v1;
  #pragma unroll
  for (int o=32;o>0;o>>=1) s1 += __shfl_down(s1,o);
  s1 = __shfl(s1,0);
  float mu = s1*(1.f/128.f);
  float d0=v0-mu, d1=v1-mu;
  float q = d0*d0+d1*d1;
  #pragma unroll
  for (int o=32;o>0;o>>=1) q += __shfl_down(q,o);
  q = __shfl(q,0);
  float rs = rsqrtf(q*(1.f/128.f)+LN_EPS);
  hS[2*t]   = gelu_ex(d0*rs*g2[2*t]+b2[2*t]);
  hS[2*t+1] = gelu_ex(d1*rs*g2[2*t+1]+b2[2*t+1]);
  __syncthreads();

  // projection (128 -> 32) on lanes 0..31, then log_softmax via shuffles
  float logit = -1e30f;
  if (t < 32){
    float a = bo[t];
    #pragma unroll 8
    for (int k=0;k<128;k++) a += hS[k]*Wo[k*32+t];
    logit = a;
  }
  float mx = logit;
  #pragma unroll
  for (int o=16;o>0;o>>=1) mx = fmaxf(mx, __shfl_xor(mx,o));
  float se = (t<32) ? expf(logit-mx) : 0.f;
  #pragma unroll
  for (int o=16;o>0;o>>=1) se += __shfl_xor(se,o);
  float lse = mx + logf(se);
  if (t < 32) out[(size_t)d*32+t] = logit - lse;
}

extern "C" void kernel_launch(void* const* d_in, const int* in_sizes, int n_in,
                              void* d_out, int out_size, void* d_ws, size_t ws_size,
                              hipStream_t stream) {
  const float* x      = (const float*)d_in[0];
  const int*   ei     = (const int*)d_in[1];
  const float* g_in   = (const float*)d_in[2];
  const float* b_in   = (const float*)d_in[3];
  const float* W1     = (const float*)d_in[4];
  const float* att1_s = (const float*)d_in[5];
  const float* att1_d = (const float*)d_in[6];
  const float* bias1  = (const float*)d_in[7];
  const float* g1     = (const float*)d_in[8];
  const float* b1     = (const float*)d_in[9];
  const float* W2     = (const float*)d_in[10];
  const float* att2_s = (const float*)d_in[11];
  const float* att2_d = (const float*)d_in[12];
  const float* bias2  = (const float*)d_in[13];
  const float* g2     = (const float*)d_in[14];
  const float* b2     = (const float*)d_in[15];
  const float* Wo     = (const float*)d_in[16];
  const float* bo     = (const float*)d_in[17];
  float* out = (float*)d_out;

  char* ws = (char*)d_ws;
  size_t off = 0;
  auto alloc = [&](size_t bytes)->char*{
    char* p = ws + off; off += (bytes + 255) & ~(size_t)255; return p;
  };
  unsigned* h0b   = (unsigned*)alloc((size_t)N_NODES*128*2);   // LN(x) bf16; reused as xh2b
  float*    xh1   = (float*)alloc((size_t)N_NODES*512*4);      // fp32 (att1); reused as xh2
  unsigned* xh1b  = (unsigned*)alloc((size_t)N_NODES*512*2);   // bf16 gather table L1
  unsigned* h1b   = (unsigned*)alloc((size_t)N_NODES*512*2);   // post-LN/GELU bf16 (GEMM2 A)
  float*    als1  = (float*)alloc((size_t)N_NODES*4*4);
  float*    ald1  = (float*)alloc((size_t)N_NODES*4*4);
  float*    als2  = (float*)alloc((size_t)N_NODES*4);
  float*    ald2  = (float*)alloc((size_t)N_NODES*4);
  int*      cnt   = (int*)alloc((size_t)N_NODES*4);
  int*      cur   = (int*)alloc((size_t)N_NODES*4);
  int*      offs  = (int*)alloc((size_t)N_NODES*4);
  int*      blksum= (int*)alloc(4096);
  int*      csr   = (int*)alloc((size_t)ETOT*4);
  float*    xh2   = xh1;            // fp32 [N,128]; xh1 dead after k_att1
  unsigned* xh2b  = h0b;            // bf16 [N,128]; h0b dead after GEMM1

  hipMemsetAsync(cnt, 0, (size_t)N_NODES*4, stream);
  hipMemsetAsync(cur, 0, (size_t)N_NODES*4, stream);

  int ebl = (ETOT + 255)/256;
  int nbl = (N_NODES + 255)/256;

  // CSR build (depends only on edge_index)
  k_count  <<<ebl,256,0,stream>>>(ei, cnt);
  k_scan1  <<<nbl,256,0,stream>>>(cnt, offs, blksum);
  k_scan2  <<<1,64,0,stream>>>(blksum, nbl);
  k_scan3  <<<nbl,256,0,stream>>>(offs, blksum);
  k_scatter<<<ebl,256,0,stream>>>(ei, offs, cur, csr);

  // layer pipeline
  k_ln_in<<<N_NODES,64,0,stream>>>(x, g_in, b_in, h0b);
  k_gemm<<<dim3(512/64,(N_NODES+127)/128),256,0,stream>>>(
      (const __hip_bfloat16*)h0b, W1, xh1, xh1b, N_NODES, 512, 128);
  k_att1<<<N_NODES,64,0,stream>>>(xh1, att1_s, att1_d, als1, ald1);
  k_gat1<<<N_NODES,256,0,stream>>>((const __hip_bfloat16*)xh1b, als1, ald1,
      offs, cnt, csr, bias1, g1, b1, h1b);
  k_gemm<<<dim3(128/64,(N_NODES+127)/128),256,0,stream>>>(
      (const __hip_bfloat16*)h1b, W2, xh2, xh2b, N_NODES, 128, 512);
  k_att2<<<N_NODES,64,0,stream>>>(xh2, att2_s, att2_d, als2, ald2);
  k_gat2_final<<<N_NODES,64,0,stream>>>((const __hip_bfloat16*)xh2b, als2, ald2,
      offs, cnt, csr, bias2, g2, b2, Wo, bo, out);
}

// Round 4
// 328.015 us; speedup vs baseline: 1.3562x; 1.1204x over previous
//
#include <hip/hip_runtime.h>
#include <hip/hip_bf16.h>
#include <math.h>

static constexpr int N_NODES = 20000;
static constexpr int N_EDGES = 320000;
static constexpr int ETOT    = N_EDGES + N_NODES;   // edges + self loops
static constexpr float LN_EPS = 1e-5f;

__device__ __forceinline__ float lrelu02(float x){ return x > 0.f ? x : 0.2f*x; }
__device__ __forceinline__ float gelu_ex(float x){ return 0.5f*x*(1.f+erff(x*0.70710678118654752f)); }
__device__ __forceinline__ float bflo(unsigned u){ return __uint_as_float(u<<16); }
__device__ __forceinline__ float bfhi(unsigned u){ return __uint_as_float(u & 0xffff0000u); }
__device__ __forceinline__ unsigned f2bf(float f){           // RNE fp32->bf16 (no NaN inputs here)
  unsigned u = __float_as_uint(f);
  return (u + 0x7fffu + ((u>>16)&1u)) >> 16;
}
__device__ __forceinline__ unsigned packbf2(float a, float b){ return f2bf(a) | (f2bf(b)<<16); }

typedef __attribute__((ext_vector_type(8))) short bf16x8;
typedef __attribute__((ext_vector_type(4))) float f32x4;

// ---------------- LN over input rows (128) -> bf16 ----------------
__global__ __launch_bounds__(64) void k_ln_in(const float* __restrict__ x,
    const float* __restrict__ g, const float* __restrict__ b, unsigned* __restrict__ out) {
  int n = blockIdx.x, t = threadIdx.x;               // block = 64, 2 ch/thread
  float2 v = ((const float2*)(x + (size_t)n*128))[t];
  float s = v.x + v.y;
  #pragma unroll
  for (int o=32;o>0;o>>=1) s += __shfl_down(s,o);
  s = __shfl(s,0);
  float mu = s*(1.f/128.f);
  float d0 = v.x-mu, d1 = v.y-mu;
  float q = d0*d0+d1*d1;
  #pragma unroll
  for (int o=32;o>0;o>>=1) q += __shfl_down(q,o);
  q = __shfl(q,0);
  float rs = rsqrtf(q*(1.f/128.f)+LN_EPS);
  float2 gg = ((const float2*)g)[t];
  float2 bb = ((const float2*)b)[t];
  out[(size_t)n*64 + t] = packbf2(d0*rs*gg.x+bb.x, d1*rs*gg.y+bb.y);
}

// ---- weight transpose + bf16 cast: Wt[n][k] = bf16(W[k][n]) ----
__global__ void k_transpose(const float* __restrict__ W, unsigned short* __restrict__ Wt,
                            int K, int N) {
  int idx = blockIdx.x*256 + threadIdx.x;
  if (idx >= K*N) return;
  int n = idx / K, k = idx - n*K;                    // write-coalesced
  Wt[idx] = (unsigned short)f2bf(W[(size_t)k*N + n]);
}

// -------- MFMA bf16 GEMM: C[M,N] = A[M,K] @ Bt[N,K]^T, fp32 C + bf16 Cb --------
// block = 4 waves; wave computes 16 rows x 64 cols; LDS-free (frags are
// contiguous 16B/lane loads from A row-major and Bt row-major).
__global__ __launch_bounds__(256) void k_gemm_mfma(
    const __hip_bfloat16* __restrict__ A,            // [M,K] bf16
    const unsigned short* __restrict__ Bt,           // [N,K] bf16
    float* __restrict__ C, unsigned short* __restrict__ Cb,
    int M, int N, int K) {
  int tid = threadIdx.x;
  int wave = tid >> 6, lane = tid & 63;
  int rowbase = blockIdx.y*64 + wave*16;
  int colbase = blockIdx.x*64;
  if (rowbase >= M) return;                          // M%16==0: wave all-or-nothing
  int l15 = lane & 15;
  int lk  = (lane >> 4) * 8;
  const __hip_bfloat16* Arow = A  + (size_t)(rowbase + l15)*K + lk;
  const unsigned short* Bcol = Bt + (size_t)(colbase + l15)*K + lk;
  f32x4 acc[4] = {};
  for (int k0 = 0; k0 < K; k0 += 32) {
    union { uint4 u; bf16x8 s; } ua, ub;
    ua.u = *(const uint4*)(Arow + k0);
    #pragma unroll
    for (int t=0;t<4;t++){
      ub.u = *(const uint4*)(Bcol + (size_t)t*16*K + k0);
      acc[t] = __builtin_amdgcn_mfma_f32_16x16x32_bf16(ua.s, ub.s, acc[t], 0,0,0);
    }
  }
  int crow = rowbase + (lane>>4)*4;                  // + reg
  #pragma unroll
  for (int t=0;t<4;t++){
    int col = colbase + t*16 + l15;
    #pragma unroll
    for (int r=0;r<4;r++){
      float v = acc[t][r];
      size_t o = (size_t)(crow + r)*N + col;
      C[o]  = v;
      Cb[o] = (unsigned short)f2bf(v);
    }
  }
}

// ---------------- attention logits, layer1 (reads fp32 xh) ----------------
__global__ __launch_bounds__(64) void k_att1(const float* __restrict__ xh,
    const float* __restrict__ as_, const float* __restrict__ ad_,
    float* __restrict__ als, float* __restrict__ ald) {
  int n = blockIdx.x, t = threadIdx.x;               // 8 ch/thread; head = t>>4
  const float* row = xh + (size_t)n*512;
  float4 v0 = ((const float4*)row)[2*t];
  float4 v1 = ((const float4*)row)[2*t+1];
  float4 w0 = ((const float4*)as_)[2*t], w1 = ((const float4*)as_)[2*t+1];
  float4 u0 = ((const float4*)ad_)[2*t], u1 = ((const float4*)ad_)[2*t+1];
  float ps = v0.x*w0.x+v0.y*w0.y+v0.z*w0.z+v0.w*w0.w
           + v1.x*w1.x+v1.y*w1.y+v1.z*w1.z+v1.w*w1.w;
  float pd = v0.x*u0.x+v0.y*u0.y+v0.z*u0.z+v0.w*u0.w
           + v1.x*u1.x+v1.y*u1.y+v1.z*u1.z+v1.w*u1.w;
  #pragma unroll
  for (int o=8;o>0;o>>=1){ ps+=__shfl_xor(ps,o); pd+=__shfl_xor(pd,o); }
  if ((t&15)==0){ int h=t>>4; als[(size_t)n*4+h]=ps; ald[(size_t)n*4+h]=pd; }
}

// ---------------- attention logits, layer2 (reads fp32 xh) ----------------
__global__ __launch_bounds__(64) void k_att2(const float* __restrict__ xh,
    const float* __restrict__ as_, const float* __restrict__ ad_,
    float* __restrict__ als, float* __restrict__ ald) {
  int n = blockIdx.x, t = threadIdx.x;               // 2 ch/thread
  float2 v = ((const float2*)(xh + (size_t)n*128))[t];
  float2 ws = ((const float2*)as_)[t], wd = ((const float2*)ad_)[t];
  float ps = v.x*ws.x+v.y*ws.y;
  float pd = v.x*wd.x+v.y*wd.y;
  #pragma unroll
  for (int o=32;o>0;o>>=1){ ps+=__shfl_down(ps,o); pd+=__shfl_down(pd,o); }
  if (t==0){ als[n]=ps; ald[n]=pd; }
}

// ---------------- CSR build ----------------
__global__ void k_count(const int* __restrict__ ei, int* __restrict__ cnt) {
  int e = blockIdx.x*256 + threadIdx.x;
  if (e < N_EDGES) atomicAdd(&cnt[ei[N_EDGES + e]], 1);
  else if (e < ETOT) atomicAdd(&cnt[e - N_EDGES], 1);
}

__global__ void k_scan1(const int* __restrict__ cnt, int* __restrict__ offs,
                        int* __restrict__ blksum) {
  __shared__ int s[256];
  int i = blockIdx.x*256 + threadIdx.x;
  int v = (i < N_NODES) ? cnt[i] : 0;
  s[threadIdx.x] = v;
  __syncthreads();
  for (int d1=1; d1<256; d1<<=1){
    int t = (threadIdx.x >= d1) ? s[threadIdx.x - d1] : 0;
    __syncthreads();
    s[threadIdx.x] += t;
    __syncthreads();
  }
  if (i < N_NODES) offs[i] = s[threadIdx.x] - v;     // exclusive
  if (threadIdx.x == 255) blksum[blockIdx.x] = s[255];
}

__global__ void k_scan2(int* __restrict__ blksum, int nb) {
  if (threadIdx.x==0 && blockIdx.x==0){
    int run=0;
    for (int i=0;i<nb;i++){ int v=blksum[i]; blksum[i]=run; run+=v; }
  }
}

__global__ void k_scan3(int* __restrict__ offs, const int* __restrict__ blksum) {
  int i = blockIdx.x*256 + threadIdx.x;
  if (i < N_NODES) offs[i] += blksum[blockIdx.x];
}

__global__ void k_scatter(const int* __restrict__ ei, const int* __restrict__ offs,
                          int* __restrict__ cur, int* __restrict__ csr) {
  int e = blockIdx.x*256 + threadIdx.x;
  int s, d;
  if (e < N_EDGES){ s = ei[e]; d = ei[N_EDGES+e]; }
  else if (e < ETOT){ s = e - N_EDGES; d = s; }
  else return;
  int pos = offs[d] + atomicAdd(&cur[d], 1);
  csr[pos] = s;
}

// ---- GAT layer 1: single-sweep softmax-aggregate + bias + LN + GELU -> bf16 ----
// one block (256 thr = 4 waves, wave w == head w) per dst node
__global__ __launch_bounds__(256) void k_gat1(
    const __hip_bfloat16* __restrict__ xh,           // [N,512] bf16
    const float* __restrict__ als, const float* __restrict__ ald, // [N,4]
    const int* __restrict__ offs, const int* __restrict__ cnt, const int* __restrict__ csr,
    const float* __restrict__ bias1, const float* __restrict__ g1, const float* __restrict__ b1,
    unsigned* __restrict__ out)                      // [N,512] bf16 (as uint pairs)
{
  int d = blockIdx.x, tid = threadIdx.x;
  int start = offs[d], deg = cnt[d];
  __shared__ float alphaS[4][64];
  __shared__ int   srcS[64];
  __shared__ float invS[4];
  __shared__ float scr[4];
  int wid = tid>>6, lane = tid&63;
  int c0 = 2*tid, c1 = 2*tid+1;                      // both channels in head `wid`
  float add = ald[(size_t)d*4 + wid];
  float den = 0.f;
  float acc0 = 0.f, acc1 = 0.f;

  for (int cb=0; cb<deg; cb+=64){
    int mm = min(64, deg-cb);
    __syncthreads();
    if (lane < mm){
      int s = csr[start+cb+lane];
      if (wid==0) srcS[lane] = s;
      float ex = expf(lrelu02(als[(size_t)s*4+wid]+add));  // logits bounded: no max pass
      alphaS[wid][lane] = ex;
      den += ex;
    }
    __syncthreads();
    int j = 0;
    for (; j+4 <= mm; j += 4){                       // 4 loads in flight
      const unsigned* r0 = (const unsigned*)(xh + (size_t)srcS[j]*512);
      const unsigned* r1 = (const unsigned*)(xh + (size_t)srcS[j+1]*512);
      const unsigned* r2 = (const unsigned*)(xh + (size_t)srcS[j+2]*512);
      const unsigned* r3 = (const unsigned*)(xh + (size_t)srcS[j+3]*512);
      unsigned u0 = r0[tid], u1 = r1[tid], u2 = r2[tid], u3 = r3[tid];
      float a0 = alphaS[wid][j],   a1 = alphaS[wid][j+1];
      float a2 = alphaS[wid][j+2], a3 = alphaS[wid][j+3];
      acc0 += a0*bflo(u0); acc1 += a0*bfhi(u0);
      acc0 += a1*bflo(u1); acc1 += a1*bfhi(u1);
      acc0 += a2*bflo(u2); acc1 += a2*bfhi(u2);
      acc0 += a3*bflo(u3); acc1 += a3*bfhi(u3);
    }
    for (; j < mm; j++){
      const unsigned* r0 = (const unsigned*)(xh + (size_t)srcS[j]*512);
      unsigned u0 = r0[tid];
      float a0 = alphaS[wid][j];
      acc0 += a0*bflo(u0); acc1 += a0*bfhi(u0);
    }
  }
  #pragma unroll
  for (int o=32;o>0;o>>=1) den += __shfl_down(den,o);
  if (lane==0) invS[wid] = 1.f/den;
  __syncthreads();
  float inv = invS[wid];
  float v0 = acc0*inv + bias1[c0];
  float v1 = acc1*inv + bias1[c1];

  // fused LN(512) + GELU, then pack bf16
  float s1 = v0+v1;
  #pragma unroll
  for (int o=32;o>0;o>>=1) s1 += __shfl_down(s1,o);
  if (lane==0) scr[wid]=s1;
  __syncthreads();
  float mu = (scr[0]+scr[1]+scr[2]+scr[3])*(1.f/512.f);
  __syncthreads();
  float d0=v0-mu, d1=v1-mu;
  float q = d0*d0+d1*d1;
  #pragma unroll
  for (int o=32;o>0;o>>=1) q += __shfl_down(q,o);
  if (lane==0) scr[wid]=q;
  __syncthreads();
  float var = (scr[0]+scr[1]+scr[2]+scr[3])*(1.f/512.f);
  float rs = rsqrtf(var+LN_EPS);
  float y0 = gelu_ex(d0*rs*g1[c0]+b1[c0]);
  float y1 = gelu_ex(d1*rs*g1[c1]+b1[c1]);
  out[(size_t)d*256 + tid] = packbf2(y0,y1);
}

// -- GAT layer 2: single-sweep aggregate + bias + LN + GELU + Wo + log_softmax --
// one block = one wave (64 thr) per dst node, 2 ch/thread
__global__ __launch_bounds__(64) void k_gat2_final(
    const __hip_bfloat16* __restrict__ xh,           // [N,128] bf16
    const float* __restrict__ als, const float* __restrict__ ald, // [N]
    const int* __restrict__ offs, const int* __restrict__ cnt, const int* __restrict__ csr,
    const float* __restrict__ bias2, const float* __restrict__ g2, const float* __restrict__ b2,
    const float* __restrict__ Wo, const float* __restrict__ bo,
    float* __restrict__ out)                         // [N,32]
{
  int d = blockIdx.x, t = threadIdx.x;
  int start = offs[d], deg = cnt[d];
  __shared__ float alphaS[64];
  __shared__ int   srcS[64];
  __shared__ float hS[128];
  float add = ald[d];
  float den = 0.f, acc0 = 0.f, acc1 = 0.f;

  for (int cb=0; cb<deg; cb+=64){
    int mm = min(64, deg-cb);
    __syncthreads();
    if (t < mm){
      int s = csr[start+cb+t];
      srcS[t] = s;
      float ex = expf(lrelu02(als[s]+add));
      alphaS[t] = ex;
      den += ex;
    }
    __syncthreads();
    int j = 0;
    for (; j+4 <= mm; j += 4){
      const unsigned* r0 = (const unsigned*)(xh + (size_t)srcS[j]*128);
      const unsigned* r1 = (const unsigned*)(xh + (size_t)srcS[j+1]*128);
      const unsigned* r2 = (const unsigned*)(xh + (size_t)srcS[j+2]*128);
      const unsigned* r3 = (const unsigned*)(xh + (size_t)srcS[j+3]*128);
      unsigned u0 = r0[t], u1 = r1[t], u2 = r2[t], u3 = r3[t];
      float a0 = alphaS[j], a1 = alphaS[j+1], a2 = alphaS[j+2], a3 = alphaS[j+3];
      acc0 += a0*bflo(u0); acc1 += a0*bfhi(u0);
      acc0 += a1*bflo(u1); acc1 += a1*bfhi(u1);
      acc0 += a2*bflo(u2); acc1 += a2*bfhi(u2);
      acc0 += a3*bflo(u3); acc1 += a3*bfhi(u3);
    }
    for (; j < mm; j++){
      const unsigned* r0 = (const unsigned*)(xh + (size_t)srcS[j]*128);
      unsigned u0 = r0[t];
      float a0 = alphaS[j];
      acc0 += a0*bflo(u0); acc1 += a0*bfhi(u0);
    }
  }
  #pragma unroll
  for (int o=32;o>0;o>>=1) den += __shfl_down(den,o);
  den = __shfl(den,0);
  float inv = 1.f/den;
  float v0 = acc0*inv + bias2[2*t];
  float v1 = acc1*inv + bias2[2*t+1];

  // LN(128) — wave-only reductions
  float s1 = v0+v1;
  #pragma unroll
  for (int o=32;o>0;o>>=1) s1 += __shfl_down(s1,o);
  s1 = __shfl(s1,0);
  float mu = s1*(1.f/128.f);
  float d0=v0-mu, d1=v1-mu;
  float q = d0*d0+d1*d1;
  #pragma unroll
  for (int o=32;o>0;o>>=1) q += __shfl_down(q,o);
  q = __shfl(q,0);
  float rs = rsqrtf(q*(1.f/128.f)+LN_EPS);
  hS[2*t]   = gelu_ex(d0*rs*g2[2*t]+b2[2*t]);
  hS[2*t+1] = gelu_ex(d1*rs*g2[2*t+1]+b2[2*t+1]);
  __syncthreads();

  // projection (128 -> 32) on lanes 0..31, then log_softmax via shuffles
  float logit = -1e30f;
  if (t < 32){
    float a = bo[t];
    #pragma unroll 8
    for (int k=0;k<128;k++) a += hS[k]*Wo[k*32+t];
    logit = a;
  }
  float mx = logit;
  #pragma unroll
  for (int o=16;o>0;o>>=1) mx = fmaxf(mx, __shfl_xor(mx,o));
  float se = (t<32) ? expf(logit-mx) : 0.f;
  #pragma unroll
  for (int o=16;o>0;o>>=1) se += __shfl_xor(se,o);
  float lse = mx + logf(se);
  if (t < 32) out[(size_t)d*32+t] = logit - lse;
}

extern "C" void kernel_launch(void* const* d_in, const int* in_sizes, int n_in,
                              void* d_out, int out_size, void* d_ws, size_t ws_size,
                              hipStream_t stream) {
  const float* x      = (const float*)d_in[0];
  const int*   ei     = (const int*)d_in[1];
  const float* g_in   = (const float*)d_in[2];
  const float* b_in   = (const float*)d_in[3];
  const float* W1     = (const float*)d_in[4];
  const float* att1_s = (const float*)d_in[5];
  const float* att1_d = (const float*)d_in[6];
  const float* bias1  = (const float*)d_in[7];
  const float* g1     = (const float*)d_in[8];
  const float* b1     = (const float*)d_in[9];
  const float* W2     = (const float*)d_in[10];
  const float* att2_s = (const float*)d_in[11];
  const float* att2_d = (const float*)d_in[12];
  const float* bias2  = (const float*)d_in[13];
  const float* g2     = (const float*)d_in[14];
  const float* b2     = (const float*)d_in[15];
  const float* Wo     = (const float*)d_in[16];
  const float* bo     = (const float*)d_in[17];
  float* out = (float*)d_out;

  char* ws = (char*)d_ws;
  size_t off = 0;
  auto alloc = [&](size_t bytes)->char*{
    char* p = ws + off; off += (bytes + 255) & ~(size_t)255; return p;
  };
  unsigned* h0b   = (unsigned*)alloc((size_t)N_NODES*128*2);   // LN(x) bf16; reused as xh2b
  float*    xh1   = (float*)alloc((size_t)N_NODES*512*4);      // fp32 (att1); reused as xh2
  unsigned short* xh1b = (unsigned short*)alloc((size_t)N_NODES*512*2); // bf16 gather table L1
  unsigned* h1b   = (unsigned*)alloc((size_t)N_NODES*512*2);   // post-LN/GELU bf16 (GEMM2 A)
  float*    als1  = (float*)alloc((size_t)N_NODES*4*4);
  float*    ald1  = (float*)alloc((size_t)N_NODES*4*4);
  float*    als2  = (float*)alloc((size_t)N_NODES*4);
  float*    ald2  = (float*)alloc((size_t)N_NODES*4);
  int*      cnt   = (int*)alloc((size_t)N_NODES*4);
  int*      cur   = (int*)alloc((size_t)N_NODES*4);
  int*      offs  = (int*)alloc((size_t)N_NODES*4);
  int*      blksum= (int*)alloc(4096);
  int*      csr   = (int*)alloc((size_t)ETOT*4);
  unsigned short* W1t = (unsigned short*)alloc((size_t)512*128*2); // [512][128] bf16
  unsigned short* W2t = (unsigned short*)alloc((size_t)128*512*2); // [128][512] bf16
  float*    xh2   = xh1;            // fp32 [N,128]; xh1 dead after k_att1
  unsigned short* xh2b = (unsigned short*)h0b; // bf16 [N,128]; h0b dead after GEMM1

  hipMemsetAsync(cnt, 0, (size_t)N_NODES*4, stream);
  hipMemsetAsync(cur, 0, (size_t)N_NODES*4, stream);

  int ebl = (ETOT + 255)/256;
  int nbl = (N_NODES + 255)/256;

  // CSR build (depends only on edge_index)
  k_count  <<<ebl,256,0,stream>>>(ei, cnt);
  k_scan1  <<<nbl,256,0,stream>>>(cnt, offs, blksum);
  k_scan2  <<<1,64,0,stream>>>(blksum, nbl);
  k_scan3  <<<nbl,256,0,stream>>>(offs, blksum);
  k_scatter<<<ebl,256,0,stream>>>(ei, offs, cur, csr);

  // weight transposes (tiny)
  k_transpose<<<(512*128+255)/256,256,0,stream>>>(W1, W1t, 128, 512);
  k_transpose<<<(128*512+255)/256,256,0,stream>>>(W2, W2t, 512, 128);

  // layer pipeline
  k_ln_in<<<N_NODES,64,0,stream>>>(x, g_in, b_in, h0b);
  k_gemm_mfma<<<dim3(512/64,(N_NODES+63)/64),256,0,stream>>>(
      (const __hip_bfloat16*)h0b, W1t, xh1, xh1b, N_NODES, 512, 128);
  k_att1<<<N_NODES,64,0,stream>>>(xh1, att1_s, att1_d, als1, ald1);
  k_gat1<<<N_NODES,256,0,stream>>>((const __hip_bfloat16*)xh1b, als1, ald1,
      offs, cnt, csr, bias1, g1, b1, h1b);
  k_gemm_mfma<<<dim3(128/64,(N_NODES+63)/64),256,0,stream>>>(
      (const __hip_bfloat16*)h1b, W2t, xh2, xh2b, N_NODES, 128, 512);
  k_att2<<<N_NODES,64,0,stream>>>(xh2, att2_s, att2_d, als2, ald2);
  k_gat2_final<<<N_NODES,64,0,stream>>>((const __hip_bfloat16*)xh2b, als2, ald2,
      offs, cnt, csr, bias2, g2, b2, Wo, bo, out);
}

// Round 5
// 327.537 us; speedup vs baseline: 1.3582x; 1.0015x over previous
//
#include <hip/hip_runtime.h>
#include <hip/hip_bf16.h>
#include <math.h>

static constexpr int N_NODES = 20000;
static constexpr int N_EDGES = 320000;
static constexpr int ETOT    = N_EDGES + N_NODES;   // edges + self loops
static constexpr float LN_EPS = 1e-5f;

__device__ __forceinline__ float lrelu02(float x){ return x > 0.f ? x : 0.2f*x; }
__device__ __forceinline__ float gelu_ex(float x){ return 0.5f*x*(1.f+erff(x*0.70710678118654752f)); }
__device__ __forceinline__ float bflo(unsigned u){ return __uint_as_float(u<<16); }
__device__ __forceinline__ float bfhi(unsigned u){ return __uint_as_float(u & 0xffff0000u); }
__device__ __forceinline__ unsigned f2bf(float f){           // RNE fp32->bf16 (no NaN inputs here)
  unsigned u = __float_as_uint(f);
  return (u + 0x7fffu + ((u>>16)&1u)) >> 16;
}
__device__ __forceinline__ unsigned packbf2(float a, float b){ return f2bf(a) | (f2bf(b)<<16); }
__device__ __forceinline__ float readlane_f(float v, int l){
  return __uint_as_float(__builtin_amdgcn_readlane(__float_as_uint(v), l));
}

typedef __attribute__((ext_vector_type(8))) short bf16x8;
typedef __attribute__((ext_vector_type(4))) float f32x4;

// ---------------- LN over input rows (128) -> bf16 ----------------
__global__ __launch_bounds__(64) void k_ln_in(const float* __restrict__ x,
    const float* __restrict__ g, const float* __restrict__ b, unsigned* __restrict__ out) {
  int n = blockIdx.x, t = threadIdx.x;               // block = 64, 2 ch/thread
  float2 v = ((const float2*)(x + (size_t)n*128))[t];
  float s = v.x + v.y;
  #pragma unroll
  for (int o=32;o>0;o>>=1) s += __shfl_down(s,o);
  s = __shfl(s,0);
  float mu = s*(1.f/128.f);
  float d0 = v.x-mu, d1 = v.y-mu;
  float q = d0*d0+d1*d1;
  #pragma unroll
  for (int o=32;o>0;o>>=1) q += __shfl_down(q,o);
  q = __shfl(q,0);
  float rs = rsqrtf(q*(1.f/128.f)+LN_EPS);
  float2 gg = ((const float2*)g)[t];
  float2 bb = ((const float2*)b)[t];
  out[(size_t)n*64 + t] = packbf2(d0*rs*gg.x+bb.x, d1*rs*gg.y+bb.y);
}

// ---- weight transpose + bf16 cast: Wt[n][k] = bf16(W[k][n]) ----
__global__ void k_transpose(const float* __restrict__ W, unsigned short* __restrict__ Wt,
                            int K, int N) {
  int idx = blockIdx.x*256 + threadIdx.x;
  if (idx >= K*N) return;
  int n = idx / K, k = idx - n*K;                    // write-coalesced
  Wt[idx] = (unsigned short)f2bf(W[(size_t)k*N + n]);
}

// -- MFMA bf16 GEMM with fused attention-logit partials --
// C = A[M,K] @ Bt[N,K]^T -> Cb bf16 only; per-row dot with a_src/a_dst
// (head width 128) accumulated into als/ald via shuffle-reduce + atomicAdd.
__global__ __launch_bounds__(256) void k_gemm_mfma_att(
    const __hip_bfloat16* __restrict__ A,            // [M,K] bf16
    const unsigned short* __restrict__ Bt,           // [N,K] bf16
    unsigned short* __restrict__ Cb,                 // [M,N] bf16
    const float* __restrict__ as_, const float* __restrict__ ad_, // [N] flat (head-major)
    float* __restrict__ als, float* __restrict__ ald,             // [M, N/128]
    int M, int N, int K) {
  int tid = threadIdx.x;
  int wave = tid >> 6, lane = tid & 63;
  int rowbase = blockIdx.y*64 + wave*16;
  int colbase = blockIdx.x*64;
  if (rowbase >= M) return;                          // M%16==0: wave all-or-nothing
  int l15 = lane & 15;
  int lk  = (lane >> 4) * 8;
  const __hip_bfloat16* Arow = A  + (size_t)(rowbase + l15)*K + lk;
  const unsigned short* Bcol = Bt + (size_t)(colbase + l15)*K + lk;
  f32x4 acc[4] = {};
  for (int k0 = 0; k0 < K; k0 += 32) {
    union { uint4 u; bf16x8 s; } ua, ub;
    ua.u = *(const uint4*)(Arow + k0);
    #pragma unroll
    for (int t=0;t<4;t++){
      ub.u = *(const uint4*)(Bcol + (size_t)t*16*K + k0);
      acc[t] = __builtin_amdgcn_mfma_f32_16x16x32_bf16(ua.s, ub.s, acc[t], 0,0,0);
    }
  }
  int crow = rowbase + (lane>>4)*4;                  // + r
  int hh = colbase >> 7, H = N >> 7;                 // 64-col block within one 128-head
  float ps[4] = {0,0,0,0}, pd[4] = {0,0,0,0};
  #pragma unroll
  for (int t=0;t<4;t++){
    int col = colbase + t*16 + l15;
    float ws = as_[col], wd = ad_[col];
    #pragma unroll
    for (int r=0;r<4;r++){
      float v = acc[t][r];
      Cb[(size_t)(crow + r)*N + col] = (unsigned short)f2bf(v);
      ps[r] += v*ws; pd[r] += v*wd;
    }
  }
  #pragma unroll
  for (int o=1;o<16;o<<=1){
    #pragma unroll
    for (int r=0;r<4;r++){ ps[r]+=__shfl_xor(ps[r],o); pd[r]+=__shfl_xor(pd[r],o); }
  }
  if (l15 == 0){
    #pragma unroll
    for (int r=0;r<4;r++){
      atomicAdd(&als[(size_t)(crow+r)*H + hh], ps[r]);
      atomicAdd(&ald[(size_t)(crow+r)*H + hh], pd[r]);
    }
  }
}

// ---------------- CSR build ----------------
__global__ void k_count(const int* __restrict__ ei, int* __restrict__ cnt) {
  int e = blockIdx.x*256 + threadIdx.x;
  if (e < N_EDGES) atomicAdd(&cnt[ei[N_EDGES + e]], 1);
  else if (e < ETOT) atomicAdd(&cnt[e - N_EDGES], 1);
}

__global__ void k_scan1(const int* __restrict__ cnt, int* __restrict__ offs,
                        int* __restrict__ blksum) {
  __shared__ int s[256];
  int i = blockIdx.x*256 + threadIdx.x;
  int v = (i < N_NODES) ? cnt[i] : 0;
  s[threadIdx.x] = v;
  __syncthreads();
  for (int d1=1; d1<256; d1<<=1){
    int t = (threadIdx.x >= d1) ? s[threadIdx.x - d1] : 0;
    __syncthreads();
    s[threadIdx.x] += t;
    __syncthreads();
  }
  if (i < N_NODES) offs[i] = s[threadIdx.x] - v;     // exclusive
  if (threadIdx.x == 255) blksum[blockIdx.x] = s[255];
}

// parallel exclusive scan of nb (<128) block sums — one block of 128 thr
__global__ void k_scan2(int* __restrict__ blksum, int nb) {
  __shared__ int s[128];
  int t = threadIdx.x;
  int v = (t < nb) ? blksum[t] : 0;
  s[t] = v;
  __syncthreads();
  for (int d1=1; d1<128; d1<<=1){
    int x = (t >= d1) ? s[t-d1] : 0;
    __syncthreads();
    s[t] += x;
    __syncthreads();
  }
  if (t < nb) blksum[t] = s[t] - v;                  // exclusive
}

__global__ void k_scan3(int* __restrict__ offs, const int* __restrict__ blksum) {
  int i = blockIdx.x*256 + threadIdx.x;
  if (i < N_NODES) offs[i] += blksum[blockIdx.x];
}

__global__ void k_scatter(const int* __restrict__ ei, const int* __restrict__ offs,
                          int* __restrict__ cur, int* __restrict__ csr) {
  int e = blockIdx.x*256 + threadIdx.x;
  int s, d;
  if (e < N_EDGES){ s = ei[e]; d = ei[N_EDGES+e]; }
  else if (e < ETOT){ s = e - N_EDGES; d = s; }
  else return;
  int pos = offs[d] + atomicAdd(&cur[d], 1);
  csr[pos] = s;
}

// ---- GAT layer 1: single-sweep softmax-aggregate + bias + LN + GELU -> bf16 ----
// one block (256 thr) per dst node. Alpha phase: wave w computes head w's exps.
// Gather phase: wave-pair grp (tid>>7) takes edges jj = grp, grp+2, ...;
// each thread carries 4 channels (uint2 / 8B). src index broadcast via readlane
// -> scalar address math + saddr loads.
__global__ __launch_bounds__(256) void k_gat1(
    const unsigned* __restrict__ xh,                 // [N,256] uint = [N,512] bf16
    const float* __restrict__ als, const float* __restrict__ ald, // [N,4]
    const int* __restrict__ offs, const int* __restrict__ cnt, const int* __restrict__ csr,
    const float* __restrict__ bias1, const float* __restrict__ g1, const float* __restrict__ b1,
    unsigned* __restrict__ out)                      // [N,256] uint = [N,512] bf16
{
  int d = blockIdx.x, tid = threadIdx.x;
  int start = offs[d], deg = cnt[d];
  __shared__ float alphaS[4][64];
  __shared__ float accS[128][4];
  __shared__ float invS[4], scr[4];
  int wid = tid>>6, lane = tid&63;
  int grp = tid>>7, u = tid&127;                     // u: channel group 4u..4u+3
  int h = u>>5;                                      // head of those channels
  float add = ald[(size_t)d*4 + wid];
  float den = 0.f;
  float acc0=0.f, acc1=0.f, acc2=0.f, acc3=0.f;

  for (int cb=0; cb<deg; cb+=64){
    int mm = min(64, deg-cb);
    __syncthreads();
    int s_e = 0;
    if (lane < mm){
      s_e = csr[start+cb+lane];
      float ex = expf(lrelu02(als[(size_t)s_e*4+wid]+add));  // logits bounded: no max pass
      alphaS[wid][lane] = ex;
      den += ex;
    }
    __syncthreads();
    for (int jj=grp; jj<mm; jj+=2){
      int s = __builtin_amdgcn_readlane(s_e, jj);    // SGPR src -> scalar addr math
      float a = alphaS[h][jj];
      uint2 v = ((const uint2*)(xh + (size_t)s*256))[u];
      acc0 += a*bflo(v.x); acc1 += a*bfhi(v.x);
      acc2 += a*bflo(v.y); acc3 += a*bfhi(v.y);
    }
  }
  #pragma unroll
  for (int o=32;o>0;o>>=1) den += __shfl_down(den,o);
  if (lane==0) invS[wid] = 1.f/den;
  if (grp==1){ accS[u][0]=acc0; accS[u][1]=acc1; accS[u][2]=acc2; accS[u][3]=acc3; }
  __syncthreads();
  float v0=0.f,v1=0.f,v2=0.f,v3=0.f, s1=0.f;
  if (grp==0){
    float inv = invS[h];
    float4 bb = *(const float4*)&bias1[4*u];
    v0 = (acc0+accS[u][0])*inv + bb.x;
    v1 = (acc1+accS[u][1])*inv + bb.y;
    v2 = (acc2+accS[u][2])*inv + bb.z;
    v3 = (acc3+accS[u][3])*inv + bb.w;
    s1 = v0+v1+v2+v3;
  }
  #pragma unroll
  for (int o=32;o>0;o>>=1) s1 += __shfl_down(s1,o);
  if (lane==0) scr[wid]=s1;
  __syncthreads();
  float mu = (scr[0]+scr[1]+scr[2]+scr[3])*(1.f/512.f);
  __syncthreads();
  float q=0.f, d0=0.f,d1=0.f,d2=0.f,d3=0.f;
  if (grp==0){ d0=v0-mu; d1=v1-mu; d2=v2-mu; d3=v3-mu; q=d0*d0+d1*d1+d2*d2+d3*d3; }
  #pragma unroll
  for (int o=32;o>0;o>>=1) q += __shfl_down(q,o);
  if (lane==0) scr[wid]=q;
  __syncthreads();
  float var = (scr[0]+scr[1]+scr[2]+scr[3])*(1.f/512.f);
  if (grp==0){
    float rs = rsqrtf(var+LN_EPS);
    float4 gg = *(const float4*)&g1[4*u];
    float4 b4 = *(const float4*)&b1[4*u];
    float y0 = gelu_ex(d0*rs*gg.x+b4.x);
    float y1 = gelu_ex(d1*rs*gg.y+b4.y);
    float y2 = gelu_ex(d2*rs*gg.z+b4.z);
    float y3 = gelu_ex(d3*rs*gg.w+b4.w);
    uint2 p; p.x = packbf2(y0,y1); p.y = packbf2(y2,y3);
    ((uint2*)(out + (size_t)d*256))[u] = p;
  }
}

// -- GAT layer 2: aggregate + bias + LN + GELU + Wo proj + log_softmax --
// 4 nodes per block (wave = node), barrier-free; src/alpha via readlane;
// projection split-K across half-waves.
__global__ __launch_bounds__(256) void k_gat2_final(
    const unsigned* __restrict__ xh,                 // [N,64] uint = [N,128] bf16
    const float* __restrict__ als, const float* __restrict__ ald, // [N]
    const int* __restrict__ offs, const int* __restrict__ cnt, const int* __restrict__ csr,
    const float* __restrict__ bias2, const float* __restrict__ g2, const float* __restrict__ b2,
    const float* __restrict__ Wo, const float* __restrict__ bo,
    float* __restrict__ out)                         // [N,32]
{
  int wave = threadIdx.x>>6, t = threadIdx.x&63;
  int d = blockIdx.x*4 + wave;
  int start = offs[d], deg = cnt[d];
  float add = ald[d];
  float den = 0.f, acc0 = 0.f, acc1 = 0.f;

  for (int cb=0; cb<deg; cb+=64){
    int mm = min(64, deg-cb);
    int s_e = 0; float ex = 0.f;
    if (t < mm){
      s_e = csr[start+cb+t];
      ex = expf(lrelu02(als[s_e]+add));
      den += ex;
    }
    for (int jj=0; jj<mm; jj++){
      int s   = __builtin_amdgcn_readlane(s_e, jj);
      float a = readlane_f(ex, jj);                  // SGPR alpha
      unsigned v = (xh + (size_t)s*64)[t];
      acc0 += a*bflo(v); acc1 += a*bfhi(v);
    }
  }
  #pragma unroll
  for (int o=32;o>0;o>>=1) den += __shfl_down(den,o);
  den = __shfl(den,0);
  float inv = 1.f/den;
  float2 bb = ((const float2*)bias2)[t];
  float v0 = acc0*inv + bb.x;
  float v1 = acc1*inv + bb.y;

  // LN(128) — wave-only reductions
  float s1 = v0+v1;
  #pragma unroll
  for (int o=32;o>0;o>>=1) s1 += __shfl_down(s1,o);
  s1 = __shfl(s1,0);
  float mu = s1*(1.f/128.f);
  float d0=v0-mu, d1=v1-mu;
  float q = d0*d0+d1*d1;
  #pragma unroll
  for (int o=32;o>0;o>>=1) q += __shfl_down(q,o);
  q = __shfl(q,0);
  float rs = rsqrtf(q*(1.f/128.f)+LN_EPS);
  float2 gg = ((const float2*)g2)[t];
  float2 b4 = ((const float2*)b2)[t];
  float y0 = gelu_ex(d0*rs*gg.x+b4.x);
  float y1 = gelu_ex(d1*rs*gg.y+b4.y);

  // projection (128->32): half-wave `half` covers k in [64*half, 64*half+64)
  int half = t>>5, c = t&31;
  int kb = half*64;
  float part = 0.f;
  #pragma unroll 8
  for (int k2=0;k2<32;k2++){
    int lsrc = (kb>>1) + k2;                         // lane holding ch kb+2k2, kb+2k2+1
    float h0 = readlane_f(y0, lsrc);
    float h1 = readlane_f(y1, lsrc);
    part += h0*Wo[(size_t)(kb+2*k2)*32 + c] + h1*Wo[(size_t)(kb+2*k2+1)*32 + c];
  }
  part += __shfl_down(part, 32);                     // lanes 0..31 hold full dot
  float logit = part + bo[c];

  // log_softmax over 32 (lanes 0..31; upper lanes compute garbage, unused)
  float mx = logit;
  #pragma unroll
  for (int o=16;o>0;o>>=1) mx = fmaxf(mx, __shfl_xor(mx,o));
  float se = expf(logit-mx);
  #pragma unroll
  for (int o=16;o>0;o>>=1) se += __shfl_xor(se,o);
  float lse = mx + logf(se);
  if (t < 32) out[(size_t)d*32+t] = logit - lse;
}

extern "C" void kernel_launch(void* const* d_in, const int* in_sizes, int n_in,
                              void* d_out, int out_size, void* d_ws, size_t ws_size,
                              hipStream_t stream) {
  const float* x      = (const float*)d_in[0];
  const int*   ei     = (const int*)d_in[1];
  const float* g_in   = (const float*)d_in[2];
  const float* b_in   = (const float*)d_in[3];
  const float* W1     = (const float*)d_in[4];
  const float* att1_s = (const float*)d_in[5];
  const float* att1_d = (const float*)d_in[6];
  const float* bias1  = (const float*)d_in[7];
  const float* g1     = (const float*)d_in[8];
  const float* b1     = (const float*)d_in[9];
  const float* W2     = (const float*)d_in[10];
  const float* att2_s = (const float*)d_in[11];
  const float* att2_d = (const float*)d_in[12];
  const float* bias2  = (const float*)d_in[13];
  const float* g2     = (const float*)d_in[14];
  const float* b2     = (const float*)d_in[15];
  const float* Wo     = (const float*)d_in[16];
  const float* bo     = (const float*)d_in[17];
  float* out = (float*)d_out;

  char* ws = (char*)d_ws;
  size_t off = 0;
  auto alloc = [&](size_t bytes)->char*{
    char* p = ws + off; off += (bytes + 255) & ~(size_t)255; return p;
  };
  unsigned* h0b   = (unsigned*)alloc((size_t)N_NODES*128*2);       // LN(x) bf16; reused as xh2b
  unsigned short* xh1b = (unsigned short*)alloc((size_t)N_NODES*512*2); // GEMM1 out bf16
  unsigned* h1b   = (unsigned*)alloc((size_t)N_NODES*512*2);       // post-LN/GELU bf16 (GEMM2 A)
  size_t att_beg = off;
  float*    als1  = (float*)alloc((size_t)N_NODES*4*4);
  float*    ald1  = (float*)alloc((size_t)N_NODES*4*4);
  float*    als2  = (float*)alloc((size_t)N_NODES*4);
  float*    ald2  = (float*)alloc((size_t)N_NODES*4);
  size_t att_end = off;
  size_t cnt_beg = off;
  int*      cnt   = (int*)alloc((size_t)N_NODES*4);
  int*      cur   = (int*)alloc((size_t)N_NODES*4);
  size_t cnt_end = off;
  int*      offs  = (int*)alloc((size_t)N_NODES*4);
  int*      blksum= (int*)alloc(4096);
  int*      csr   = (int*)alloc((size_t)ETOT*4);
  unsigned short* W1t = (unsigned short*)alloc((size_t)512*128*2); // [512][128] bf16
  unsigned short* W2t = (unsigned short*)alloc((size_t)128*512*2); // [128][512] bf16
  unsigned* xh2b  = h0b;                                           // bf16 [N,64] uints; h0b dead after GEMM1

  hipMemsetAsync(ws + att_beg, 0, att_end - att_beg, stream);      // als/ald zero
  hipMemsetAsync(ws + cnt_beg, 0, cnt_end - cnt_beg, stream);      // cnt/cur zero

  int ebl = (ETOT + 255)/256;
  int nbl = (N_NODES + 255)/256;

  // CSR build (depends only on edge_index)
  k_count  <<<ebl,256,0,stream>>>(ei, cnt);
  k_scan1  <<<nbl,256,0,stream>>>(cnt, offs, blksum);
  k_scan2  <<<1,128,0,stream>>>(blksum, nbl);
  k_scan3  <<<nbl,256,0,stream>>>(offs, blksum);
  k_scatter<<<ebl,256,0,stream>>>(ei, offs, cur, csr);

  // weight transposes (tiny)
  k_transpose<<<(512*128+255)/256,256,0,stream>>>(W1, W1t, 128, 512);
  k_transpose<<<(128*512+255)/256,256,0,stream>>>(W2, W2t, 512, 128);

  // layer pipeline
  k_ln_in<<<N_NODES,64,0,stream>>>(x, g_in, b_in, h0b);
  k_gemm_mfma_att<<<dim3(512/64,(N_NODES+63)/64),256,0,stream>>>(
      (const __hip_bfloat16*)h0b, W1t, xh1b, att1_s, att1_d, als1, ald1,
      N_NODES, 512, 128);
  k_gat1<<<N_NODES,256,0,stream>>>((const unsigned*)xh1b, als1, ald1,
      offs, cnt, csr, bias1, g1, b1, h1b);
  k_gemm_mfma_att<<<dim3(128/64,(N_NODES+63)/64),256,0,stream>>>(
      (const __hip_bfloat16*)h1b, W2t, (unsigned short*)xh2b, att2_s, att2_d,
      als2, ald2, N_NODES, 128, 512);
  k_gat2_final<<<N_NODES/4,256,0,stream>>>(xh2b, als2, ald2,
      offs, cnt, csr, bias2, g2, b2, Wo, bo, out);
}

// Round 6
// 303.433 us; speedup vs baseline: 1.4661x; 1.0794x over previous
//
#include <hip/hip_runtime.h>
#include <hip/hip_bf16.h>
#include <math.h>

static constexpr int N_NODES = 20000;
static constexpr int N_EDGES = 320000;
static constexpr int ETOT    = N_EDGES + N_NODES;   // edges + self loops
static constexpr float LN_EPS = 1e-5f;

__device__ __forceinline__ float lrelu02(float x){ return x > 0.f ? x : 0.2f*x; }
__device__ __forceinline__ float gelu_ex(float x){ return 0.5f*x*(1.f+erff(x*0.70710678118654752f)); }
__device__ __forceinline__ float bflo(unsigned u){ return __uint_as_float(u<<16); }
__device__ __forceinline__ float bfhi(unsigned u){ return __uint_as_float(u & 0xffff0000u); }
__device__ __forceinline__ unsigned f2bf(float f){           // RNE fp32->bf16
  unsigned u = __float_as_uint(f);
  return (u + 0x7fffu + ((u>>16)&1u)) >> 16;
}
__device__ __forceinline__ unsigned packbf2(float a, float b){ return f2bf(a) | (f2bf(b)<<16); }
__device__ __forceinline__ float readlane_f(float v, int l){
  return __uint_as_float(__builtin_amdgcn_readlane(__float_as_uint(v), l));
}

typedef __attribute__((ext_vector_type(8))) short bf16x8;
typedef __attribute__((ext_vector_type(4))) float f32x4;

// ---------------- CSR: count in-degrees ----------------
__global__ void k_count(const int* __restrict__ ei, int* __restrict__ cnt) {
  int e = blockIdx.x*256 + threadIdx.x;
  if (e < N_EDGES) atomicAdd(&cnt[ei[N_EDGES + e]], 1);
  else if (e < ETOT) atomicAdd(&cnt[e - N_EDGES], 1);
}

// ---- CSR scan (per-256 exclusive) + zero attention-logit buffers ----
static constexpr int NBL = (N_NODES + 255)/256;     // 79 scan blocks
__global__ void k_scan1x(const int* __restrict__ cnt, int* __restrict__ offs,
                         int* __restrict__ blksum, int* __restrict__ attZero,
                         int attInts) {
  if ((int)blockIdx.x >= NBL){                      // zeroing branch
    int i = ((int)blockIdx.x - NBL)*256 + threadIdx.x;
    if (i < attInts) attZero[i] = 0;
    return;
  }
  __shared__ int s[256];
  int i = blockIdx.x*256 + threadIdx.x;
  int v = (i < N_NODES) ? cnt[i] : 0;
  s[threadIdx.x] = v;
  __syncthreads();
  for (int d1=1; d1<256; d1<<=1){
    int t = (threadIdx.x >= d1) ? s[threadIdx.x - d1] : 0;
    __syncthreads();
    s[threadIdx.x] += t;
    __syncthreads();
  }
  if (i < N_NODES) offs[i] = s[threadIdx.x] - v;    // exclusive within block
  if (threadIdx.x == 255) blksum[blockIdx.x] = s[255];
}

// parallel exclusive scan of NBL (<128) block sums — one block of 128 thr
__global__ void k_scan2(int* __restrict__ blksum) {
  __shared__ int s[128];
  int t = threadIdx.x;
  int v = (t < NBL) ? blksum[t] : 0;
  s[t] = v;
  __syncthreads();
  for (int d1=1; d1<128; d1<<=1){
    int x = (t >= d1) ? s[t-d1] : 0;
    __syncthreads();
    s[t] += x;
    __syncthreads();
  }
  if (t < NBL) blksum[t] = s[t] - v;                // exclusive
}

// ---- mega kernel: CSR scatter + both weight transposes + input LN ----
static constexpr int EBL = (ETOT + 255)/256;        // 1329 scatter blocks
static constexpr int TB1 = 512*128/256;             // 256 blocks W1t
static constexpr int TB2 = 512*128/256;             // 256 blocks W2t
static constexpr int LNB = N_NODES/4;               // 5000 LN blocks (4 rows ea)
__global__ __launch_bounds__(256) void k_mega(
    const int* __restrict__ ei, const int* __restrict__ offs,
    const int* __restrict__ blk, int* __restrict__ cur, int* __restrict__ csr,
    const float* __restrict__ W1, unsigned short* __restrict__ W1t,
    const float* __restrict__ W2, unsigned short* __restrict__ W2t,
    const float* __restrict__ x, const float* __restrict__ g_in,
    const float* __restrict__ b_in, unsigned* __restrict__ h0b) {
  int b = blockIdx.x, tid = threadIdx.x;
  if (b < EBL){                                     // scatter
    int e = b*256 + tid;
    int s, d;
    if (e < N_EDGES){ s = ei[e]; d = ei[N_EDGES+e]; }
    else if (e < ETOT){ s = e - N_EDGES; d = s; }
    else return;
    int pos = offs[d] + blk[d>>8] + atomicAdd(&cur[d], 1);
    csr[pos] = s;
    return;
  }
  if (b < EBL + TB1){                               // W1t[n][k]=bf16(W1[k][n]) K=128,N=512
    int idx = (b-EBL)*256 + tid;
    int n = idx >> 7, k = idx & 127;
    W1t[idx] = (unsigned short)f2bf(W1[(size_t)k*512 + n]);
    return;
  }
  if (b < EBL + TB1 + TB2){                         // W2t K=512,N=128
    int idx = (b-EBL-TB1)*256 + tid;
    int n = idx >> 9, k = idx & 511;
    W2t[idx] = (unsigned short)f2bf(W2[(size_t)k*128 + n]);
    return;
  }
  // LN over 128-ch rows -> bf16; wave = row, 2 ch/lane
  int row = (b - EBL - TB1 - TB2)*4 + (tid>>6);
  int t = tid & 63;
  float2 v = ((const float2*)(x + (size_t)row*128))[t];
  float s = v.x + v.y;
  #pragma unroll
  for (int o=32;o>0;o>>=1) s += __shfl_down(s,o);
  s = __shfl(s,0);
  float mu = s*(1.f/128.f);
  float d0 = v.x-mu, d1 = v.y-mu;
  float q = d0*d0+d1*d1;
  #pragma unroll
  for (int o=32;o>0;o>>=1) q += __shfl_down(q,o);
  q = __shfl(q,0);
  float rs = rsqrtf(q*(1.f/128.f)+LN_EPS);
  float2 gg = ((const float2*)g_in)[t];
  float2 bb = ((const float2*)b_in)[t];
  h0b[(size_t)row*64 + t] = packbf2(d0*rs*gg.x+bb.x, d1*rs*gg.y+bb.y);
}

// -- MFMA bf16 GEMM with fused attention-logit partials --
// C = A[M,K] @ Bt[N,K]^T. Cb (bf16) and/or Cf (fp32) written if non-null.
// Per-row dot with a_src/a_dst (head width 128) -> atomicAdd into als/ald.
__global__ __launch_bounds__(256) void k_gemm_mfma_att(
    const __hip_bfloat16* __restrict__ A,            // [M,K] bf16
    const unsigned short* __restrict__ Bt,           // [N,K] bf16
    unsigned short* __restrict__ Cb, float* __restrict__ Cf,
    const float* __restrict__ as_, const float* __restrict__ ad_, // [N] flat
    float* __restrict__ als, float* __restrict__ ald,             // [M, N/128]
    int M, int N, int K) {
  int tid = threadIdx.x;
  int wave = tid >> 6, lane = tid & 63;
  int rowbase = blockIdx.y*64 + wave*16;
  int colbase = blockIdx.x*64;
  if (rowbase >= M) return;                          // M%16==0: wave all-or-nothing
  int l15 = lane & 15;
  int lk  = (lane >> 4) * 8;
  const __hip_bfloat16* Arow = A  + (size_t)(rowbase + l15)*K + lk;
  const unsigned short* Bcol = Bt + (size_t)(colbase + l15)*K + lk;
  f32x4 acc[4] = {};
  for (int k0 = 0; k0 < K; k0 += 32) {
    union { uint4 u; bf16x8 s; } ua, ub;
    ua.u = *(const uint4*)(Arow + k0);
    #pragma unroll
    for (int t=0;t<4;t++){
      ub.u = *(const uint4*)(Bcol + (size_t)t*16*K + k0);
      acc[t] = __builtin_amdgcn_mfma_f32_16x16x32_bf16(ua.s, ub.s, acc[t], 0,0,0);
    }
  }
  int crow = rowbase + (lane>>4)*4;                  // + r
  int hh = colbase >> 7, H = N >> 7;
  float ps[4] = {0,0,0,0}, pd[4] = {0,0,0,0};
  #pragma unroll
  for (int t=0;t<4;t++){
    int col = colbase + t*16 + l15;
    float ws = as_[col], wd = ad_[col];
    #pragma unroll
    for (int r=0;r<4;r++){
      float v = acc[t][r];
      size_t o = (size_t)(crow + r)*N + col;
      if (Cb) Cb[o] = (unsigned short)f2bf(v);
      if (Cf) Cf[o] = v;
      ps[r] += v*ws; pd[r] += v*wd;
    }
  }
  #pragma unroll
  for (int o=1;o<16;o<<=1){
    #pragma unroll
    for (int r=0;r<4;r++){ ps[r]+=__shfl_xor(ps[r],o); pd[r]+=__shfl_xor(pd[r],o); }
  }
  if (l15 == 0){
    #pragma unroll
    for (int r=0;r<4;r++){
      atomicAdd(&als[(size_t)(crow+r)*H + hh], ps[r]);
      atomicAdd(&ald[(size_t)(crow+r)*H + hh], pd[r]);
    }
  }
}

// ---- GAT layer 1: single-sweep softmax-aggregate + bias + LN + GELU -> bf16 ----
// one block (256 thr = 4 waves, wave w == head w) per dst node.
// Round-4 proven inner loop: LDS alpha/src, 4-deep unrolled vector gather.
__global__ __launch_bounds__(256) void k_gat1(
    const unsigned* __restrict__ xh,                 // [N,256] uint = [N,512] bf16
    const float* __restrict__ als, const float* __restrict__ ald, // [N,4]
    const int* __restrict__ offs, const int* __restrict__ blk,
    const int* __restrict__ cnt, const int* __restrict__ csr,
    const float* __restrict__ bias1, const float* __restrict__ g1, const float* __restrict__ b1,
    unsigned* __restrict__ out)                      // [N,256] uint
{
  int d = blockIdx.x, tid = threadIdx.x;
  int start = offs[d] + blk[d>>8], deg = cnt[d];
  __shared__ float alphaS[4][64];
  __shared__ int   srcS[64];
  __shared__ float invS[4];
  __shared__ float scr[4];
  int wid = tid>>6, lane = tid&63;
  int c0 = 2*tid, c1 = 2*tid+1;                      // both channels in head `wid`
  float add = ald[(size_t)d*4 + wid];
  float den = 0.f;
  float acc0 = 0.f, acc1 = 0.f;

  for (int cb=0; cb<deg; cb+=64){
    int mm = min(64, deg-cb);
    __syncthreads();
    if (lane < mm){
      int s = csr[start+cb+lane];
      if (wid==0) srcS[lane] = s;
      float ex = expf(lrelu02(als[(size_t)s*4+wid]+add));  // logits bounded: no max pass
      alphaS[wid][lane] = ex;
      den += ex;
    }
    __syncthreads();
    int j = 0;
    for (; j+4 <= mm; j += 4){                       // 4 loads in flight
      const unsigned* r0 = xh + (size_t)srcS[j]*256;
      const unsigned* r1 = xh + (size_t)srcS[j+1]*256;
      const unsigned* r2 = xh + (size_t)srcS[j+2]*256;
      const unsigned* r3 = xh + (size_t)srcS[j+3]*256;
      unsigned u0 = r0[tid], u1 = r1[tid], u2 = r2[tid], u3 = r3[tid];
      float a0 = alphaS[wid][j],   a1 = alphaS[wid][j+1];
      float a2 = alphaS[wid][j+2], a3 = alphaS[wid][j+3];
      acc0 += a0*bflo(u0); acc1 += a0*bfhi(u0);
      acc0 += a1*bflo(u1); acc1 += a1*bfhi(u1);
      acc0 += a2*bflo(u2); acc1 += a2*bfhi(u2);
      acc0 += a3*bflo(u3); acc1 += a3*bfhi(u3);
    }
    for (; j < mm; j++){
      unsigned u0 = (xh + (size_t)srcS[j]*256)[tid];
      float a0 = alphaS[wid][j];
      acc0 += a0*bflo(u0); acc1 += a0*bfhi(u0);
    }
  }
  #pragma unroll
  for (int o=32;o>0;o>>=1) den += __shfl_down(den,o);
  if (lane==0) invS[wid] = 1.f/den;
  __syncthreads();
  float inv = invS[wid];
  float v0 = acc0*inv + bias1[c0];
  float v1 = acc1*inv + bias1[c1];

  // fused LN(512) + GELU, then pack bf16
  float s1 = v0+v1;
  #pragma unroll
  for (int o=32;o>0;o>>=1) s1 += __shfl_down(s1,o);
  if (lane==0) scr[wid]=s1;
  __syncthreads();
  float mu = (scr[0]+scr[1]+scr[2]+scr[3])*(1.f/512.f);
  __syncthreads();
  float d0=v0-mu, d1=v1-mu;
  float q = d0*d0+d1*d1;
  #pragma unroll
  for (int o=32;o>0;o>>=1) q += __shfl_down(q,o);
  if (lane==0) scr[wid]=q;
  __syncthreads();
  float var = (scr[0]+scr[1]+scr[2]+scr[3])*(1.f/512.f);
  float rs = rsqrtf(var+LN_EPS);
  float y0 = gelu_ex(d0*rs*g1[c0]+b1[c0]);
  float y1 = gelu_ex(d1*rs*g1[c1]+b1[c1]);
  out[(size_t)d*256 + tid] = packbf2(y0,y1);
}

// -- GAT layer 2: aggregate (fp32 table) + bias + LN + GELU + Wo + log_softmax --
// 4 nodes per block (wave = node); LDS alpha/src per wave; 4-unrolled gather.
__global__ __launch_bounds__(256) void k_gat2_final(
    const float* __restrict__ xh,                    // [N,128] fp32
    const float* __restrict__ als, const float* __restrict__ ald, // [N]
    const int* __restrict__ offs, const int* __restrict__ blk,
    const int* __restrict__ cnt, const int* __restrict__ csr,
    const float* __restrict__ bias2, const float* __restrict__ g2, const float* __restrict__ b2,
    const float* __restrict__ Wo, const float* __restrict__ bo,
    float* __restrict__ out)                         // [N,32]
{
  int wave = threadIdx.x>>6, t = threadIdx.x&63;
  int d = blockIdx.x*4 + wave;
  int start = offs[d] + blk[d>>8], deg = cnt[d];
  __shared__ float alphaS[4][64];
  __shared__ int   srcS[4][64];
  float add = ald[d];
  float den = 0.f, acc0 = 0.f, acc1 = 0.f;

  for (int cb=0; cb<deg; cb+=64){
    int mm = min(64, deg-cb);
    if (t < mm){
      int s = csr[start+cb+t];
      srcS[wave][t] = s;
      float ex = expf(lrelu02(als[s]+add));
      alphaS[wave][t] = ex;
      den += ex;
    }
    int j = 0;
    for (; j+4 <= mm; j += 4){
      float2 f0 = ((const float2*)(xh + (size_t)srcS[wave][j]*128))[t];
      float2 f1 = ((const float2*)(xh + (size_t)srcS[wave][j+1]*128))[t];
      float2 f2 = ((const float2*)(xh + (size_t)srcS[wave][j+2]*128))[t];
      float2 f3 = ((const float2*)(xh + (size_t)srcS[wave][j+3]*128))[t];
      float a0 = alphaS[wave][j],   a1 = alphaS[wave][j+1];
      float a2 = alphaS[wave][j+2], a3 = alphaS[wave][j+3];
      acc0 += a0*f0.x; acc1 += a0*f0.y;
      acc0 += a1*f1.x; acc1 += a1*f1.y;
      acc0 += a2*f2.x; acc1 += a2*f2.y;
      acc0 += a3*f3.x; acc1 += a3*f3.y;
    }
    for (; j < mm; j++){
      float2 f0 = ((const float2*)(xh + (size_t)srcS[wave][j]*128))[t];
      float a0 = alphaS[wave][j];
      acc0 += a0*f0.x; acc1 += a0*f0.y;
    }
  }
  #pragma unroll
  for (int o=32;o>0;o>>=1) den += __shfl_down(den,o);
  den = __shfl(den,0);
  float inv = 1.f/den;
  float2 bb = ((const float2*)bias2)[t];
  float v0 = acc0*inv + bb.x;
  float v1 = acc1*inv + bb.y;

  // LN(128) — wave-only reductions
  float s1 = v0+v1;
  #pragma unroll
  for (int o=32;o>0;o>>=1) s1 += __shfl_down(s1,o);
  s1 = __shfl(s1,0);
  float mu = s1*(1.f/128.f);
  float d0=v0-mu, d1=v1-mu;
  float q = d0*d0+d1*d1;
  #pragma unroll
  for (int o=32;o>0;o>>=1) q += __shfl_down(q,o);
  q = __shfl(q,0);
  float rs = rsqrtf(q*(1.f/128.f)+LN_EPS);
  float2 gg = ((const float2*)g2)[t];
  float2 b4 = ((const float2*)b2)[t];
  float y0 = gelu_ex(d0*rs*gg.x+b4.x);
  float y1 = gelu_ex(d1*rs*gg.y+b4.y);

  // projection (128->32): half-wave `half` covers k in [64*half, 64*half+64)
  int half = t>>5, c = t&31;
  int kb = half*64;
  float part = 0.f;
  #pragma unroll 8
  for (int k2=0;k2<32;k2++){
    int lsrc = (kb>>1) + k2;                         // lane holding ch kb+2k2, kb+2k2+1
    float h0 = readlane_f(y0, lsrc);
    float h1 = readlane_f(y1, lsrc);
    part += h0*Wo[(size_t)(kb+2*k2)*32 + c] + h1*Wo[(size_t)(kb+2*k2+1)*32 + c];
  }
  part += __shfl_down(part, 32);                     // lanes 0..31 hold full dot
  float logit = part + bo[c];

  // log_softmax over 32 (lanes 0..31)
  float mx = logit;
  #pragma unroll
  for (int o=16;o>0;o>>=1) mx = fmaxf(mx, __shfl_xor(mx,o));
  float se = expf(logit-mx);
  #pragma unroll
  for (int o=16;o>0;o>>=1) se += __shfl_xor(se,o);
  float lse = mx + logf(se);
  if (t < 32) out[(size_t)d*32+t] = logit - lse;
}

extern "C" void kernel_launch(void* const* d_in, const int* in_sizes, int n_in,
                              void* d_out, int out_size, void* d_ws, size_t ws_size,
                              hipStream_t stream) {
  const float* x      = (const float*)d_in[0];
  const int*   ei     = (const int*)d_in[1];
  const float* g_in   = (const float*)d_in[2];
  const float* b_in   = (const float*)d_in[3];
  const float* W1     = (const float*)d_in[4];
  const float* att1_s = (const float*)d_in[5];
  const float* att1_d = (const float*)d_in[6];
  const float* bias1  = (const float*)d_in[7];
  const float* g1     = (const float*)d_in[8];
  const float* b1     = (const float*)d_in[9];
  const float* W2     = (const float*)d_in[10];
  const float* att2_s = (const float*)d_in[11];
  const float* att2_d = (const float*)d_in[12];
  const float* bias2  = (const float*)d_in[13];
  const float* g2     = (const float*)d_in[14];
  const float* b2     = (const float*)d_in[15];
  const float* Wo     = (const float*)d_in[16];
  const float* bo     = (const float*)d_in[17];
  float* out = (float*)d_out;

  char* ws = (char*)d_ws;
  size_t off = 0;
  auto alloc = [&](size_t bytes)->char*{
    char* p = ws + off; off += (bytes + 255) & ~(size_t)255; return p;
  };
  unsigned* h0b   = (unsigned*)alloc((size_t)N_NODES*128*2);       // LN(x) bf16
  unsigned short* xh1b = (unsigned short*)alloc((size_t)N_NODES*512*2); // GEMM1 out bf16
  unsigned* h1b   = (unsigned*)alloc((size_t)N_NODES*512*2);       // post-LN/GELU bf16
  float*    xh2f  = (float*)alloc((size_t)N_NODES*128*4);          // GEMM2 out fp32
  size_t att_beg = off;
  float*    als1  = (float*)alloc((size_t)N_NODES*4*4);
  float*    ald1  = (float*)alloc((size_t)N_NODES*4*4);
  float*    als2  = (float*)alloc((size_t)N_NODES*4);
  float*    ald2  = (float*)alloc((size_t)N_NODES*4);
  size_t att_end = off;
  size_t cnt_beg = off;
  int*      cnt   = (int*)alloc((size_t)N_NODES*4);
  int*      cur   = (int*)alloc((size_t)N_NODES*4);
  size_t cnt_end = off;
  int*      offs  = (int*)alloc((size_t)N_NODES*4);
  int*      blksum= (int*)alloc(4096);
  int*      csr   = (int*)alloc((size_t)ETOT*4);
  unsigned short* W1t = (unsigned short*)alloc((size_t)512*128*2); // [512][128] bf16
  unsigned short* W2t = (unsigned short*)alloc((size_t)128*512*2); // [128][512] bf16

  int attInts = (int)((att_end - att_beg)/4);
  int zbl = (attInts + 255)/256;

  hipMemsetAsync(ws + cnt_beg, 0, cnt_end - cnt_beg, stream);      // cnt/cur zero

  // 1. degree count
  k_count  <<<EBL,256,0,stream>>>(ei, cnt);
  // 2. per-block scan + zero att logits
  k_scan1x <<<NBL + zbl,256,0,stream>>>(cnt, offs, blksum, (int*)(ws+att_beg), attInts);
  // 3. block-sum exclusive scan
  k_scan2  <<<1,128,0,stream>>>(blksum);
  // 4. scatter + weight transposes + input LN (independent work, one dispatch)
  k_mega   <<<EBL + TB1 + TB2 + LNB,256,0,stream>>>(
      ei, offs, blksum, cur, csr, W1, W1t, W2, W2t, x, g_in, b_in, h0b);
  // 5. GEMM1 (bf16 out) + fused att1 logits
  k_gemm_mfma_att<<<dim3(512/64,(N_NODES+63)/64),256,0,stream>>>(
      (const __hip_bfloat16*)h0b, W1t, xh1b, nullptr, att1_s, att1_d,
      als1, ald1, N_NODES, 512, 128);
  // 6. GAT layer 1
  k_gat1<<<N_NODES,256,0,stream>>>((const unsigned*)xh1b, als1, ald1,
      offs, blksum, cnt, csr, bias1, g1, b1, h1b);
  // 7. GEMM2 (fp32 out) + fused att2 logits
  k_gemm_mfma_att<<<dim3(128/64,(N_NODES+63)/64),256,0,stream>>>(
      (const __hip_bfloat16*)h1b, W2t, nullptr, xh2f, att2_s, att2_d,
      als2, ald2, N_NODES, 128, 512);
  // 8. GAT layer 2 + Wo projection + log_softmax
  k_gat2_final<<<N_NODES/4,256,0,stream>>>(xh2f, als2, ald2,
      offs, blksum, cnt, csr, bias2, g2, b2, Wo, bo, out);
}

// Round 7
// 276.718 us; speedup vs baseline: 1.6076x; 1.0965x over previous
//
#include <hip/hip_runtime.h>
#include <hip/hip_bf16.h>
#include <math.h>

static constexpr int N_NODES = 20000;
static constexpr int N_EDGES = 320000;
static constexpr int ETOT    = N_EDGES + N_NODES;   // edges + self loops
static constexpr float LN_EPS = 1e-5f;

__device__ __forceinline__ float lrelu02(float x){ return x > 0.f ? x : 0.2f*x; }
__device__ __forceinline__ float gelu_ex(float x){ return 0.5f*x*(1.f+erff(x*0.70710678118654752f)); }
__device__ __forceinline__ float bflo(unsigned u){ return __uint_as_float(u<<16); }
__device__ __forceinline__ float bfhi(unsigned u){ return __uint_as_float(u & 0xffff0000u); }
__device__ __forceinline__ unsigned f2bf(float f){           // RNE fp32->bf16
  unsigned u = __float_as_uint(f);
  return (u + 0x7fffu + ((u>>16)&1u)) >> 16;
}
__device__ __forceinline__ unsigned packbf2(float a, float b){ return f2bf(a) | (f2bf(b)<<16); }
__device__ __forceinline__ float readlane_f(float v, int l){
  return __uint_as_float(__builtin_amdgcn_readlane(__float_as_uint(v), l));
}

typedef __attribute__((ext_vector_type(8))) short bf16x8;
typedef __attribute__((ext_vector_type(4))) float f32x4;

// ---- mega kernel: ELL build (atomic slots) + weight transposes + input LN ----
static constexpr int EBL = (ETOT + 255)/256;        // 1329 edge blocks
static constexpr int TB1 = 512*128/256;             // 256 blocks W1t
static constexpr int TB2 = 512*128/256;             // 256 blocks W2t
static constexpr int LNB = N_NODES/4;               // 5000 LN blocks (4 rows ea)
__global__ __launch_bounds__(256) void k_build_mega(
    const int* __restrict__ ei, int* __restrict__ cnt, int* __restrict__ ell,
    const float* __restrict__ W1, unsigned short* __restrict__ W1t,
    const float* __restrict__ W2, unsigned short* __restrict__ W2t,
    const float* __restrict__ x, const float* __restrict__ g_in,
    const float* __restrict__ b_in, unsigned* __restrict__ h0b) {
  int b = blockIdx.x, tid = threadIdx.x;
  if (b < EBL){                                     // ELL scatter (deg<=64 w.h.p.)
    int e = b*256 + tid;
    int s, d;
    if (e < N_EDGES){ s = ei[e]; d = ei[N_EDGES+e]; }
    else if (e < ETOT){ s = e - N_EDGES; d = s; }
    else return;
    int pos = atomicAdd(&cnt[d], 1);
    if (pos < 64) ell[d*64 + pos] = s;
    return;
  }
  if (b < EBL + TB1){                               // W1t[n][k]=bf16(W1[k][n]) K=128,N=512
    int idx = (b-EBL)*256 + tid;
    int n = idx >> 7, k = idx & 127;
    W1t[idx] = (unsigned short)f2bf(W1[(size_t)k*512 + n]);
    return;
  }
  if (b < EBL + TB1 + TB2){                         // W2t K=512,N=128
    int idx = (b-EBL-TB1)*256 + tid;
    int n = idx >> 9, k = idx & 511;
    W2t[idx] = (unsigned short)f2bf(W2[(size_t)k*128 + n]);
    return;
  }
  // LN over 128-ch rows -> bf16; wave = row, 2 ch/lane
  int row = (b - EBL - TB1 - TB2)*4 + (tid>>6);
  int t = tid & 63;
  float2 v = ((const float2*)(x + (size_t)row*128))[t];
  float s = v.x + v.y;
  #pragma unroll
  for (int o=32;o>0;o>>=1) s += __shfl_down(s,o);
  s = __shfl(s,0);
  float mu = s*(1.f/128.f);
  float d0 = v.x-mu, d1 = v.y-mu;
  float q = d0*d0+d1*d1;
  #pragma unroll
  for (int o=32;o>0;o>>=1) q += __shfl_down(q,o);
  q = __shfl(q,0);
  float rs = rsqrtf(q*(1.f/128.f)+LN_EPS);
  float2 gg = ((const float2*)g_in)[t];
  float2 bb = ((const float2*)b_in)[t];
  h0b[(size_t)row*64 + t] = packbf2(d0*rs*gg.x+bb.x, d1*rs*gg.y+bb.y);
}

// -- MFMA bf16 GEMM, BN=128 (one head per block): Cb bf16 + DETERMINISTIC
//    per-head attention logits via in-wave shuffle reduce + plain store. --
__global__ __launch_bounds__(256) void k_gemm_mfma_att(
    const __hip_bfloat16* __restrict__ A,            // [M,K] bf16
    const unsigned short* __restrict__ Bt,           // [N,K] bf16
    unsigned short* __restrict__ Cb,                 // [M,N] bf16
    const float* __restrict__ as_, const float* __restrict__ ad_, // [N]
    float* __restrict__ als, float* __restrict__ ald,             // [M, N/128]
    int M, int N, int K) {
  int tid = threadIdx.x;
  int wave = tid >> 6, lane = tid & 63;
  int rowbase = blockIdx.y*64 + wave*16;
  int head = blockIdx.x;
  int colbase = head*128;
  if (rowbase >= M) return;                          // M%16==0: wave all-or-nothing
  int l15 = lane & 15;
  int lk  = (lane >> 4) * 8;
  const __hip_bfloat16* Arow = A  + (size_t)(rowbase + l15)*K + lk;
  const unsigned short* Bcol = Bt + (size_t)(colbase + l15)*K + lk;
  f32x4 acc[8] = {};
  for (int k0 = 0; k0 < K; k0 += 32) {
    union { uint4 u; bf16x8 s; } ua, ub;
    ua.u = *(const uint4*)(Arow + k0);
    #pragma unroll
    for (int t=0;t<8;t++){
      ub.u = *(const uint4*)(Bcol + (size_t)t*16*K + k0);
      acc[t] = __builtin_amdgcn_mfma_f32_16x16x32_bf16(ua.s, ub.s, acc[t], 0,0,0);
    }
  }
  int crow = rowbase + (lane>>4)*4;                  // + r
  int H = N >> 7;
  float ps[4] = {0,0,0,0}, pd[4] = {0,0,0,0};
  #pragma unroll
  for (int t=0;t<8;t++){
    int col = colbase + t*16 + l15;
    float ws = as_[col], wd = ad_[col];
    #pragma unroll
    for (int r=0;r<4;r++){
      float v = acc[t][r];
      Cb[(size_t)(crow + r)*N + col] = (unsigned short)f2bf(v);
      ps[r] += v*ws; pd[r] += v*wd;
    }
  }
  #pragma unroll
  for (int o=1;o<16;o<<=1){
    #pragma unroll
    for (int r=0;r<4;r++){ ps[r]+=__shfl_xor(ps[r],o); pd[r]+=__shfl_xor(pd[r],o); }
  }
  if (l15 == 0){
    #pragma unroll
    for (int r=0;r<4;r++){
      als[(size_t)(crow+r)*H + head] = ps[r];
      ald[(size_t)(crow+r)*H + head] = pd[r];
    }
  }
}

// ---- GAT layer 1: wave covers full 1KB row via uint4; 4 edges/wave in flight ----
// block (256 thr) per dst node; wave w == head w. lane = 16*sub + p:
// sub = edge slot (j = jb+sub), p = 16B chunk -> channels w*128 + p*8 .. +8.
__global__ __launch_bounds__(256) void k_gat1(
    const uint4* __restrict__ xh,                    // [N][64] uint4 = [N,512] bf16
    const float* __restrict__ als, const float* __restrict__ ald, // [N,4]
    const int* __restrict__ cnt, const int* __restrict__ ell,     // [N], [N*64]
    const float* __restrict__ bias1, const float* __restrict__ g1, const float* __restrict__ b1,
    uint4* __restrict__ out)                         // [N][64] uint4
{
  int d = blockIdx.x, tid = threadIdx.x;
  int wave = tid>>6, lane = tid&63;
  __shared__ float alphaS[4][64];
  __shared__ int   srcS[64];
  __shared__ float invS[4], scrA[4], scrB[4];
  int deg = min(cnt[d], 64);

  // alpha phase: wave = head; zero-fill beyond deg
  {
    float ex = 0.f; int s = 0;
    if (lane < deg){
      s = ell[d*64 + lane];
      ex = expf(lrelu02(als[(size_t)s*4 + wave] + ald[(size_t)d*4 + wave]));
    }
    alphaS[wave][lane] = ex;
    if (wave==0) srcS[lane] = s;                     // 0 for lane>=deg
    float den = ex;
    #pragma unroll
    for (int o=32;o>0;o>>=1) den += __shfl_down(den,o);
    if (lane==0) invS[wave] = 1.f/den;
  }
  __syncthreads();

  int sub = lane>>4, p = lane&15;
  int ci = wave*16 + p;                              // uint4 index within row
  float acc[8] = {};
  int degR = (deg + 7) & ~7;                         // <=64; pads are alpha=0,src=0
  for (int jb=0; jb<degR; jb+=8){
    int j0 = jb + sub, j1 = jb + 4 + sub;
    int s0 = srcS[j0], s1 = srcS[j1];
    float a0 = alphaS[wave][j0], a1 = alphaS[wave][j1];
    uint4 v0 = xh[(size_t)s0*64 + ci];
    uint4 v1 = xh[(size_t)s1*64 + ci];
    acc[0]+=a0*bflo(v0.x); acc[1]+=a0*bfhi(v0.x);
    acc[2]+=a0*bflo(v0.y); acc[3]+=a0*bfhi(v0.y);
    acc[4]+=a0*bflo(v0.z); acc[5]+=a0*bfhi(v0.z);
    acc[6]+=a0*bflo(v0.w); acc[7]+=a0*bfhi(v0.w);
    acc[0]+=a1*bflo(v1.x); acc[1]+=a1*bfhi(v1.x);
    acc[2]+=a1*bflo(v1.y); acc[3]+=a1*bfhi(v1.y);
    acc[4]+=a1*bflo(v1.z); acc[5]+=a1*bfhi(v1.z);
    acc[6]+=a1*bflo(v1.w); acc[7]+=a1*bfhi(v1.w);
  }
  // reduce the 4 edge-subsets (lanes p, p+16, p+32, p+48 share channels)
  #pragma unroll
  for (int i=0;i<8;i++){
    acc[i] += __shfl_xor(acc[i],16);
    acc[i] += __shfl_xor(acc[i],32);
  }
  float inv = invS[wave];
  int cbase = wave*128 + p*8;
  float4 bb0 = *(const float4*)&bias1[cbase];
  float4 bb1 = *(const float4*)&bias1[cbase+4];
  float v[8];
  v[0]=acc[0]*inv+bb0.x; v[1]=acc[1]*inv+bb0.y;
  v[2]=acc[2]*inv+bb0.z; v[3]=acc[3]*inv+bb0.w;
  v[4]=acc[4]*inv+bb1.x; v[5]=acc[5]*inv+bb1.y;
  v[6]=acc[6]*inv+bb1.z; v[7]=acc[7]*inv+bb1.w;
  // fused LN(512): per-wave (=head) partial sums via 16-group xor reduce
  float s1 = v[0]+v[1]+v[2]+v[3]+v[4]+v[5]+v[6]+v[7];
  #pragma unroll
  for (int o=1;o<16;o<<=1) s1 += __shfl_xor(s1,o);
  if (lane==0) scrA[wave] = s1;
  __syncthreads();
  float mu = (scrA[0]+scrA[1]+scrA[2]+scrA[3])*(1.f/512.f);
  float q = 0.f;
  #pragma unroll
  for (int i=0;i<8;i++){ float dd = v[i]-mu; q += dd*dd; }
  #pragma unroll
  for (int o=1;o<16;o<<=1) q += __shfl_xor(q,o);
  if (lane==0) scrB[wave] = q;
  __syncthreads();
  float var = (scrB[0]+scrB[1]+scrB[2]+scrB[3])*(1.f/512.f);
  float rs = rsqrtf(var+LN_EPS);
  if (sub==0){                                       // 16 lanes/wave store 256B
    float4 gg0 = *(const float4*)&g1[cbase];
    float4 gg1 = *(const float4*)&g1[cbase+4];
    float4 b40 = *(const float4*)&b1[cbase];
    float4 b41 = *(const float4*)&b1[cbase+4];
    float y0 = gelu_ex((v[0]-mu)*rs*gg0.x+b40.x);
    float y1 = gelu_ex((v[1]-mu)*rs*gg0.y+b40.y);
    float y2 = gelu_ex((v[2]-mu)*rs*gg0.z+b40.z);
    float y3 = gelu_ex((v[3]-mu)*rs*gg0.w+b40.w);
    float y4 = gelu_ex((v[4]-mu)*rs*gg1.x+b41.x);
    float y5 = gelu_ex((v[5]-mu)*rs*gg1.y+b41.y);
    float y6 = gelu_ex((v[6]-mu)*rs*gg1.z+b41.z);
    float y7 = gelu_ex((v[7]-mu)*rs*gg1.w+b41.w);
    uint4 pk;
    pk.x = packbf2(y0,y1); pk.y = packbf2(y2,y3);
    pk.z = packbf2(y4,y5); pk.w = packbf2(y6,y7);
    out[(size_t)d*64 + ci] = pk;
  }
}

// -- GAT layer 2: bf16 table, 4 nodes/block (wave=node), round-4 gather;
//    LN + GELU + Wo projection + log_softmax all wave-local. --
__global__ __launch_bounds__(256) void k_gat2_final(
    const unsigned* __restrict__ xh,                 // [N,64] uint = [N,128] bf16
    const float* __restrict__ als, const float* __restrict__ ald, // [N]
    const int* __restrict__ cnt, const int* __restrict__ ell,
    const float* __restrict__ bias2, const float* __restrict__ g2, const float* __restrict__ b2,
    const float* __restrict__ Wo, const float* __restrict__ bo,
    float* __restrict__ out)                         // [N,32]
{
  int wave = threadIdx.x>>6, t = threadIdx.x&63;
  int d = blockIdx.x*4 + wave;
  int deg = min(cnt[d], 64);
  __shared__ float alphaS[4][64];
  __shared__ int   srcS[4][64];
  float add = ald[d];
  float den = 0.f, acc0 = 0.f, acc1 = 0.f;
  {
    float ex = 0.f; int s = 0;
    if (t < deg){
      s = ell[d*64 + t];
      ex = expf(lrelu02(als[s]+add));
      den = ex;
    }
    alphaS[wave][t] = ex;
    srcS[wave][t] = s;
  }
  int degR = (deg + 3) & ~3;
  for (int j=0; j<degR; j+=4){
    int s0=srcS[wave][j], s1=srcS[wave][j+1], s2=srcS[wave][j+2], s3=srcS[wave][j+3];
    float a0=alphaS[wave][j], a1=alphaS[wave][j+1], a2=alphaS[wave][j+2], a3=alphaS[wave][j+3];
    unsigned u0 = xh[(size_t)s0*64 + t];
    unsigned u1 = xh[(size_t)s1*64 + t];
    unsigned u2 = xh[(size_t)s2*64 + t];
    unsigned u3 = xh[(size_t)s3*64 + t];
    acc0 += a0*bflo(u0); acc1 += a0*bfhi(u0);
    acc0 += a1*bflo(u1); acc1 += a1*bfhi(u1);
    acc0 += a2*bflo(u2); acc1 += a2*bfhi(u2);
    acc0 += a3*bflo(u3); acc1 += a3*bfhi(u3);
  }
  #pragma unroll
  for (int o=32;o>0;o>>=1) den += __shfl_down(den,o);
  den = __shfl(den,0);
  float inv = 1.f/den;
  float2 bb = ((const float2*)bias2)[t];
  float v0 = acc0*inv + bb.x;
  float v1 = acc1*inv + bb.y;

  // LN(128) — wave-only reductions
  float s1 = v0+v1;
  #pragma unroll
  for (int o=32;o>0;o>>=1) s1 += __shfl_down(s1,o);
  s1 = __shfl(s1,0);
  float mu = s1*(1.f/128.f);
  float d0=v0-mu, d1=v1-mu;
  float q = d0*d0+d1*d1;
  #pragma unroll
  for (int o=32;o>0;o>>=1) q += __shfl_down(q,o);
  q = __shfl(q,0);
  float rs = rsqrtf(q*(1.f/128.f)+LN_EPS);
  float2 gg = ((const float2*)g2)[t];
  float2 b4 = ((const float2*)b2)[t];
  float y0 = gelu_ex(d0*rs*gg.x+b4.x);
  float y1 = gelu_ex(d1*rs*gg.y+b4.y);

  // projection (128->32): half-wave `half` covers k in [64*half, 64*half+64)
  int half = t>>5, c = t&31;
  int kb = half*64;
  float part = 0.f;
  #pragma unroll 8
  for (int k2=0;k2<32;k2++){
    int lsrc = (kb>>1) + k2;                         // lane holding ch kb+2k2, kb+2k2+1
    float h0 = readlane_f(y0, lsrc);
    float h1 = readlane_f(y1, lsrc);
    part += h0*Wo[(size_t)(kb+2*k2)*32 + c] + h1*Wo[(size_t)(kb+2*k2+1)*32 + c];
  }
  part += __shfl_down(part, 32);                     // lanes 0..31 hold full dot
  float logit = part + bo[c];

  // log_softmax over 32 (lanes 0..31)
  float mx = logit;
  #pragma unroll
  for (int o=16;o>0;o>>=1) mx = fmaxf(mx, __shfl_xor(mx,o));
  float se = expf(logit-mx);
  #pragma unroll
  for (int o=16;o>0;o>>=1) se += __shfl_xor(se,o);
  float lse = mx + logf(se);
  if (t < 32) out[(size_t)d*32+t] = logit - lse;
}

extern "C" void kernel_launch(void* const* d_in, const int* in_sizes, int n_in,
                              void* d_out, int out_size, void* d_ws, size_t ws_size,
                              hipStream_t stream) {
  const float* x      = (const float*)d_in[0];
  const int*   ei     = (const int*)d_in[1];
  const float* g_in   = (const float*)d_in[2];
  const float* b_in   = (const float*)d_in[3];
  const float* W1     = (const float*)d_in[4];
  const float* att1_s = (const float*)d_in[5];
  const float* att1_d = (const float*)d_in[6];
  const float* bias1  = (const float*)d_in[7];
  const float* g1     = (const float*)d_in[8];
  const float* b1     = (const float*)d_in[9];
  const float* W2     = (const float*)d_in[10];
  const float* att2_s = (const float*)d_in[11];
  const float* att2_d = (const float*)d_in[12];
  const float* bias2  = (const float*)d_in[13];
  const float* g2     = (const float*)d_in[14];
  const float* b2     = (const float*)d_in[15];
  const float* Wo     = (const float*)d_in[16];
  const float* bo     = (const float*)d_in[17];
  float* out = (float*)d_out;

  char* ws = (char*)d_ws;
  size_t off = 0;
  auto alloc = [&](size_t bytes)->char*{
    char* p = ws + off; off += (bytes + 255) & ~(size_t)255; return p;
  };
  unsigned* h0b   = (unsigned*)alloc((size_t)N_NODES*128*2);       // LN(x) bf16
  unsigned short* xh1b = (unsigned short*)alloc((size_t)N_NODES*512*2); // GEMM1 out bf16
  unsigned* h1b   = (unsigned*)alloc((size_t)N_NODES*512*2);       // post-LN/GELU bf16
  unsigned short* xh2b = (unsigned short*)alloc((size_t)N_NODES*128*2); // GEMM2 out bf16
  float*    als1  = (float*)alloc((size_t)N_NODES*4*4);
  float*    ald1  = (float*)alloc((size_t)N_NODES*4*4);
  float*    als2  = (float*)alloc((size_t)N_NODES*4);
  float*    ald2  = (float*)alloc((size_t)N_NODES*4);
  int*      cnt   = (int*)alloc((size_t)N_NODES*4);
  int*      ell   = (int*)alloc((size_t)N_NODES*64*4);             // ELL adjacency
  unsigned short* W1t = (unsigned short*)alloc((size_t)512*128*2); // [512][128] bf16
  unsigned short* W2t = (unsigned short*)alloc((size_t)128*512*2); // [128][512] bf16

  hipMemsetAsync(cnt, 0, (size_t)N_NODES*4, stream);

  // 1. ELL build + weight transposes + input LN (independent work, one dispatch)
  k_build_mega<<<EBL + TB1 + TB2 + LNB,256,0,stream>>>(
      ei, cnt, ell, W1, W1t, W2, W2t, x, g_in, b_in, h0b);
  // 2. GEMM1 (bf16 out) + deterministic att1 logits (4 head-blocks x 313)
  k_gemm_mfma_att<<<dim3(4,(N_NODES+63)/64),256,0,stream>>>(
      (const __hip_bfloat16*)h0b, W1t, xh1b, att1_s, att1_d,
      als1, ald1, N_NODES, 512, 128);
  // 3. GAT layer 1
  k_gat1<<<N_NODES,256,0,stream>>>((const uint4*)xh1b, als1, ald1,
      cnt, ell, bias1, g1, b1, (uint4*)h1b);
  // 4. GEMM2 (bf16 out) + att2 logits (1 head-block x 313)
  k_gemm_mfma_att<<<dim3(1,(N_NODES+63)/64),256,0,stream>>>(
      (const __hip_bfloat16*)h1b, W2t, xh2b, att2_s, att2_d,
      als2, ald2, N_NODES, 128, 512);
  // 5. GAT layer 2 + Wo projection + log_softmax
  k_gat2_final<<<N_NODES/4,256,0,stream>>>((const unsigned*)xh2b, als2, ald2,
      cnt, ell, bias2, g2, b2, Wo, bo, out);
}